// Round 9
// baseline (5191.570 us; speedup 1.0000x reference)
//
#include <hip/hip_runtime.h>
#include <math.h>

#define D_MODEL 768
#define D_INNER 1536
#define B_SZ 4
#define T_SZ 512
#define ROWS (B_SZ*T_SZ)   // 2048
#define XP_N 80
#define CH 16              // scan chunks
#define CT 32              // T per chunk
#define XS 8               // x_proj split-K factor
#define XKC (D_INNER/XS)   // 192
#define OS 4               // out_proj split-K factor
#define OKC (D_INNER/OS)   // 384
#define MN_OUT (ROWS*768)  // 1572864
#define NBLK 512           // persistent-kernel grid (2 blocks/CU, capacity-guaranteed resident)

typedef __attribute__((ext_vector_type(8))) short bf16x8;
typedef __attribute__((ext_vector_type(4))) float f32x4;

#define GLL(g, l) __builtin_amdgcn_global_load_lds( \
    (const __attribute__((address_space(1))) void*)(g), \
    (__attribute__((address_space(3))) void*)(l), 16, 0, 0)

__device__ __forceinline__ float sigmoidf_(float x){ return 1.0f/(1.0f+__expf(-x)); }
__device__ __forceinline__ float siluf_(float x){ return x*sigmoidf_(x); }
__device__ __forceinline__ unsigned short f2bf(float f){
  unsigned u = __builtin_bit_cast(unsigned, f);
  u = (u + 0x7FFFu + ((u >> 16) & 1u)) >> 16;   // RNE
  return (unsigned short)u;
}
__device__ __forceinline__ ushort4 cvt4(float4 v){
  ushort4 r; r.x=f2bf(v.x); r.y=f2bf(v.y); r.z=f2bf(v.z); r.w=f2bf(v.w); return r;
}

// ---- software grid barrier (all NBLK blocks resident by capacity) ----
__device__ __forceinline__ void gsync(unsigned* bar, int bi){
  __syncthreads();
  if (threadIdx.x == 0){
    __threadfence();   // agent-scope release: L2 writeback of this XCD's stores
    __hip_atomic_fetch_add(bar + bi, 1u, __ATOMIC_RELEASE, __HIP_MEMORY_SCOPE_AGENT);
    while (__hip_atomic_load(bar + bi, __ATOMIC_ACQUIRE, __HIP_MEMORY_SCOPE_AGENT) < NBLK)
      __builtin_amdgcn_s_sleep(2);
    __threadfence();   // acquire side: invalidate stale lines
  }
  __syncthreads();
}

// ---------------- one-time cast of ALL layer weights to bf16 (w/ padding) ----------------
#define CA_N0 9437184LL
#define CA_N1 4718592LL
#define CA_N2 196608LL
#define CA_N3 786432LL
#define CA_N4 393216LL
__global__ __launch_bounds__(256) void cast_all(
    const float* __restrict__ ipw, unsigned short* __restrict__ wbi,
    const float* __restrict__ opw, unsigned short* __restrict__ wbo,
    const float* __restrict__ inpw, unsigned short* __restrict__ inpwb,
    const float* __restrict__ xpw, unsigned short* __restrict__ xpwb,
    const float* __restrict__ dtw, unsigned short* __restrict__ dtwb)
{
  long long i4 = ((long long)blockIdx.x*256 + threadIdx.x)*4;
  if (i4 < CA_N0){ *(ushort4*)(wbi + i4) = cvt4(*(const float4*)(ipw + i4)); return; }
  i4 -= CA_N0;
  if (i4 < CA_N1){ *(ushort4*)(wbo + i4) = cvt4(*(const float4*)(opw + i4)); return; }
  i4 -= CA_N1;
  if (i4 < CA_N2){ *(ushort4*)(inpwb + i4) = cvt4(*(const float4*)(inpw + i4)); return; }
  i4 -= CA_N2;
  if (i4 < CA_N3){
    const long long l = i4 / (128*1536), rem = i4 % (128*1536);
    const long long r = rem / 1536, k = rem % 1536;
    ushort4 o;
    if (r < 80) o = cvt4(*(const float4*)(xpw + (l*80 + r)*1536 + k));
    else { o.x=0;o.y=0;o.z=0;o.w=0; }
    *(ushort4*)(xpwb + i4) = o; return;
  }
  i4 -= CA_N3;
  if (i4 < CA_N4){
    const long long l = i4 / (1536*64), rem = i4 % (1536*64);
    const long long r = rem / 64, c = rem % 64;
    ushort4 o;
    if (c < 48) o = cvt4(*(const float4*)(dtw + (l*1536 + r)*48 + c));
    else { o.x=0;o.y=0;o.z=0;o.w=0; }
    *(ushort4*)(dtwb + i4) = o;
  }
}

// ---------------- transpose: x (B,256,512) -> xtb (B,512,256) bf16 ----------------
__global__ void transpose_x(const float* __restrict__ x, unsigned short* __restrict__ xtb){
  __shared__ float s[32][33];
  int b = blockIdx.z;
  int t0 = blockIdx.x*32, c0 = blockIdx.y*32;
  int tx = threadIdx.x, ty = threadIdx.y;
  s[ty][tx] = x[((size_t)b*256 + (c0+ty))*512 + (t0+tx)];
  __syncthreads();
  xtb[((size_t)b*512 + (t0+ty))*256 + (c0+tx)] = f2bf(s[tx][ty]);
}

// ---------------- standalone input GEMM (once, before mega) ----------------
__global__ __launch_bounds__(256) void gemm_input(
    const unsigned short* __restrict__ A, const unsigned short* __restrict__ Wb,
    const float* __restrict__ bias, float* __restrict__ C)
{
  __shared__ unsigned short As[128*32];
  __shared__ unsigned short Ws[128*32];
  const int tid = threadIdx.x;
  const int bm = blockIdx.y*128, bn = blockIdx.x*128;
  const int wave = tid >> 6, lane = tid & 63;
  const int wm = (wave >> 1)*64, wn = (wave & 1)*64;
  const int fr = lane & 15, quad = lane >> 4;
  f32x4 acc[4][4] = {};
  const int row0 = (wave*64 + lane) >> 2;
  const int khl  = ((lane & 3) + 4 - ((row0 >> 1) & 3)) & 3;
  const unsigned short* Ag = A  + (size_t)(bm + row0)*256 + khl*8;
  const unsigned short* Wg = Wb + (size_t)(bn + row0)*256 + khl*8;
  const size_t rstep = (size_t)64*256;
  unsigned short* ldsA = As + wave*512;
  unsigned short* ldsW = Ws + wave*512;
  for (int k0 = 0; k0 < 256; k0 += 32){
    GLL(Ag + k0,          ldsA);
    GLL(Ag + rstep + k0,  ldsA + 2048);
    GLL(Wg + k0,          ldsW);
    GLL(Wg + rstep + k0,  ldsW + 2048);
    __syncthreads();
    bf16x8 a[4], b[4];
    #pragma unroll
    for (int i=0;i<4;i++){
      const int row = wm + i*16 + fr;
      a[i] = *(const bf16x8*)(As + row*32 + (((quad + (row>>1)) & 3)*8));
    }
    #pragma unroll
    for (int j=0;j<4;j++){
      const int row = wn + j*16 + fr;
      b[j] = *(const bf16x8*)(Ws + row*32 + (((quad + (row>>1)) & 3)*8));
    }
    #pragma unroll
    for (int i=0;i<4;i++)
      #pragma unroll
      for (int j=0;j<4;j++)
        acc[i][j] = __builtin_amdgcn_mfma_f32_16x16x32_bf16(a[i], b[j], acc[i][j], 0, 0, 0);
    __syncthreads();
  }
  #pragma unroll
  for (int i=0;i<4;i++){
    #pragma unroll
    for (int r=0;r<4;r++){
      const int row = bm + wm + i*16 + quad*4 + r;
      #pragma unroll
      for (int j=0;j<4;j++){
        const int col = bn + wn + j*16 + fr;
        C[(size_t)row*768 + col] = acc[i][j][r] + bias[col];
      }
    }
  }
}

// ---------------- shared MFMA K-loop for mega stages ----------------
__device__ __forceinline__ void kloop(
    const unsigned short* __restrict__ Ag, const unsigned short* __restrict__ Wg,
    size_t rstepA, size_t rstepW, int K,
    unsigned short* As, unsigned short* Ws, int woff,
    int wm, int wn, int fr, int quad, f32x4 acc[4][4])
{
  for (int k0 = 0; k0 < K; k0 += 32){
    GLL(Ag + k0,           As + woff);
    GLL(Ag + rstepA + k0,  As + woff + 2048);
    GLL(Wg + k0,           Ws + woff);
    GLL(Wg + rstepW + k0,  Ws + woff + 2048);
    __syncthreads();
    bf16x8 a[4], b[4];
    #pragma unroll
    for (int i=0;i<4;i++){
      const int row = wm + i*16 + fr;
      a[i] = *(const bf16x8*)(As + row*32 + (((quad + (row>>1)) & 3)*8));
    }
    #pragma unroll
    for (int j=0;j<4;j++){
      const int row = wn + j*16 + fr;
      b[j] = *(const bf16x8*)(Ws + row*32 + (((quad + (row>>1)) & 3)*8));
    }
    #pragma unroll
    for (int i=0;i<4;i++)
      #pragma unroll
      for (int j=0;j<4;j++)
        acc[i][j] = __builtin_amdgcn_mfma_f32_16x16x32_bf16(a[i], b[j], acc[i][j], 0, 0, 0);
    __syncthreads();
  }
}

// ---------------- persistent whole-network kernel (4 layers + head) ----------------
__global__ __launch_bounds__(256, 2) void mamba_mega(
    const float* __restrict__ conv_w, const float* __restrict__ conv_b,
    const float* __restrict__ dt_proj_b, const float* __restrict__ A_log,
    const float* __restrict__ D_param, const float* __restrict__ norm_w,
    const float* __restrict__ norm_f_w, const float* __restrict__ cls_w,
    const float* __restrict__ cls_b,
    const unsigned short* __restrict__ wbi, const unsigned short* __restrict__ wbo,
    const unsigned short* __restrict__ wxp, const unsigned short* __restrict__ wdt,
    float* resid, float* normed, float* hidden, float* xz, float* ucv,
    float* xp, float* delta, unsigned short* ybf, unsigned short* ubf,
    unsigned short* xpb, float* xpart, float* ppool, float* out,
    unsigned* bar)
{
  __shared__ unsigned short As[128*32];
  __shared__ unsigned short Ws[128*32];
  __shared__ float sred[4];
  __shared__ float lspool[768];

  const int tid = threadIdx.x;
  const int blk = blockIdx.x;
  const int wave = tid >> 6, lane = tid & 63;
  const int wm = (wave >> 1)*64, wn = (wave & 1)*64;
  const int fr = lane & 15, quad = lane >> 4;
  const int row0g = (wave*64 + lane) >> 2;
  const int khl = ((lane & 3) + 4 - ((row0g >> 1) & 3)) & 3;
  const int woff = wave*512;
  const int lane64 = tid & 63, wv = tid >> 6;
  unsigned short* normedb = (unsigned short*)normed;
  float* Pend = normed;     // dead between in_proj and next fused_norm
  float* Hend = hidden;
  int bi = 0;

  for (int l = 0; l < 4; l++){
    // ---- S1: fused_norm: resid += out_proj partials (l>0), normedb = rmsnorm ----
    {
      const float* P0 = l ? delta : nullptr;
      const float* P1 = ucv;
      const float* w = norm_w + (size_t)l*768;
      for (int row = blk; row < 2048; row += NBLK){
        float v[3]; float ss = 0.f;
        #pragma unroll
        for (int i=0;i<3;i++){
          const int c = tid + i*256;
          const size_t idx = (size_t)row*768 + c;
          float r = resid[idx];
          if (P0) r += (P0[idx] + P0[MN_OUT + idx]) + (P1[idx] + P1[MN_OUT + idx]);
          v[i] = r; ss += r*r;
        }
        #pragma unroll
        for (int off=32; off>=1; off>>=1) ss += __shfl_xor(ss, off);
        if (lane64 == 0) sred[wv] = ss;
        __syncthreads();
        const float tot = sred[0]+sred[1]+sred[2]+sred[3];
        const float scale = rsqrtf(tot*(1.0f/768.0f) + 1e-5f);
        #pragma unroll
        for (int i=0;i<3;i++){
          const int c = tid + i*256;
          const size_t idx = (size_t)row*768 + c;
          if (P0) resid[idx] = v[i];
          normedb[idx] = f2bf(v[i]*scale*w[c]);
        }
        __syncthreads();
      }
      gsync(bar, bi++);
    }
    // ---- S2: in_proj: normedb @ wbi_l^T -> xz fp32 (384 tiles) ----
    {
      const unsigned short* Wl = wbi + (size_t)l*3072*768;
      for (int vb = blk; vb < 384; vb += NBLK){
        const int bm = (vb / 24)*128, bn = (vb % 24)*128;
        f32x4 acc[4][4] = {};
        const unsigned short* Ag = normedb + (size_t)(bm + row0g)*768 + khl*8;
        const unsigned short* Wg = Wl + (size_t)(bn + row0g)*768 + khl*8;
        kloop(Ag, Wg, (size_t)64*768, (size_t)64*768, 768, As, Ws, woff, wm, wn, fr, quad, acc);
        #pragma unroll
        for (int i=0;i<4;i++)
          #pragma unroll
          for (int r=0;r<4;r++){
            const int row = bm + wm + i*16 + quad*4 + r;
            float* Cp = xz + (size_t)row*3072 + bn + wn + fr;
            #pragma unroll
            for (int j=0;j<4;j++) Cp[j*16] = acc[i][j][r];
          }
      }
      gsync(bar, bi++);
    }
    // ---- S3: conv_silu -> ucv fp32 + ubf bf16 (3.1M elems, 24 iters) ----
    {
      const float* cw = conv_w + (size_t)l*1536*4;
      const float* cb = conv_b + (size_t)l*1536;
      for (int idx = blk*256 + tid; idx < ROWS*D_INNER; idx += NBLK*256){
        const int d = idx % D_INNER;
        const int row = idx / D_INNER;
        const int t = row & (T_SZ-1);
        float acc = cb[d];
        #pragma unroll
        for (int k=0;k<4;k++){
          const int tt = t - 3 + k;
          if (tt >= 0) acc += xz[(size_t)(row - 3 + k)*3072 + d] * cw[d*4 + k];
        }
        const float s = siluf_(acc);
        ucv[idx] = s;
        ubf[idx] = f2bf(s);
      }
      gsync(bar, bi++);
    }
    // ---- S4: x_proj split-K: ubf @ wxp_l^T -> xpart (128 tiles) ----
    {
      const unsigned short* Wl = wxp + (size_t)l*128*1536;
      for (int vb = blk; vb < 16*XS; vb += NBLK){
        const int bm = (vb % 16)*128, s = vb / 16;
        const int koff = s*XKC;
        f32x4 acc[4][4] = {};
        const unsigned short* Ag = ubf + (size_t)(bm + row0g)*D_INNER + koff + khl*8;
        const unsigned short* Wg = Wl + (size_t)row0g*D_INNER + koff + khl*8;
        kloop(Ag, Wg, (size_t)64*D_INNER, (size_t)64*D_INNER, XKC, As, Ws, woff, wm, wn, fr, quad, acc);
        #pragma unroll
        for (int i=0;i<4;i++)
          #pragma unroll
          for (int r=0;r<4;r++){
            const int row = bm + wm + i*16 + quad*4 + r;
            #pragma unroll
            for (int j=0;j<4;j++){
              const int col = wn + j*16 + fr;
              if (col < XP_N)
                xpart[((size_t)s*ROWS + row)*XP_N + col] = acc[i][j][r];
            }
          }
      }
      gsync(bar, bi++);
    }
    // ---- S5: reduce xpart -> xp fp32 + xpb bf16 ----
    {
      for (int i = blk*256 + tid; i < ROWS*XP_N; i += NBLK*256){
        const int row = i / XP_N, c = i % XP_N;
        float s = 0.f;
        #pragma unroll
        for (int k=0;k<XS;k++) s += xpart[(size_t)k*ROWS*XP_N + i];
        xp[i] = s;
        if (c < 48) xpb[row*64 + c] = f2bf(s);
        else if (c < 64) xpb[row*64 + c] = 0;
      }
      gsync(bar, bi++);
    }
    // ---- S6: dt_proj (K=64) + bias + softplus -> delta fp32 (192 tiles) ----
    {
      const unsigned short* Wl = wdt + (size_t)l*1536*64;
      const float* bias = dt_proj_b + (size_t)l*1536;
      for (int vb = blk; vb < 192; vb += NBLK){
        const int bm = (vb / 12)*128, bn = (vb % 12)*128;
        f32x4 acc[4][4] = {};
        const unsigned short* Ag = xpb + (size_t)(bm + row0g)*64 + khl*8;
        const unsigned short* Wg = Wl + (size_t)(bn + row0g)*64 + khl*8;
        kloop(Ag, Wg, (size_t)64*64, (size_t)64*64, 64, As, Ws, woff, wm, wn, fr, quad, acc);
        #pragma unroll
        for (int i=0;i<4;i++)
          #pragma unroll
          for (int r=0;r<4;r++){
            const int row = bm + wm + i*16 + quad*4 + r;
            float* Cp = delta + (size_t)row*D_INNER + bn + wn + fr;
            #pragma unroll
            for (int j=0;j<4;j++){
              const int col = bn + wn + j*16 + fr;
              float v = acc[i][j][r] + bias[col];
              v = (v > 20.f) ? v : log1pf(__expf(v));
              Cp[j*16] = v;
            }
          }
      }
      gsync(bar, bi++);
    }
    // ---- S7: scan pass1 (360 vblocks) ----
    {
      const float* alog = A_log + (size_t)l*1536*16;
      for (int vb = blk; vb < 6*B_SZ*(CH-1); vb += NBLK){
        const int x = vb % 6, b = (vb/6) % B_SZ, c = vb / (6*B_SZ);
        const int d = x*256 + tid;
        float4 t0 = *(const float4*)(alog + d*16 + 0);
        float4 t1 = *(const float4*)(alog + d*16 + 4);
        float4 t2 = *(const float4*)(alog + d*16 + 8);
        float4 t3 = *(const float4*)(alog + d*16 + 12);
        float Av[16] = {t0.x,t0.y,t0.z,t0.w,t1.x,t1.y,t1.z,t1.w,
                        t2.x,t2.y,t2.z,t2.w,t3.x,t3.y,t3.z,t3.w};
        float h[16], P[16];
        #pragma unroll
        for (int n=0;n<16;n++){ Av[n] = -__expf(Av[n]); h[n]=0.f; P[n]=1.f; }
        const size_t r0 = (size_t)b*T_SZ + (size_t)c*CT;
        const float* dp = delta + r0*D_INNER + d;
        const float* up = ucv  + r0*D_INNER + d;
        const float* bp = xp   + r0*XP_N + 48;
        for (int t=0;t<CT;t++){
          const float dv = dp[(size_t)t*D_INNER];
          const float uv = up[(size_t)t*D_INNER];
          const float4 B0 = *(const float4*)(bp + (size_t)t*XP_N);
          const float4 B1 = *(const float4*)(bp + (size_t)t*XP_N + 4);
          const float4 B2 = *(const float4*)(bp + (size_t)t*XP_N + 8);
          const float4 B3 = *(const float4*)(bp + (size_t)t*XP_N + 12);
          const float Bv[16] = {B0.x,B0.y,B0.z,B0.w,B1.x,B1.y,B1.z,B1.w,
                                B2.x,B2.y,B2.z,B2.w,B3.x,B3.y,B3.z,B3.w};
          const float du = dv*uv;
          #pragma unroll
          for (int n=0;n<16;n++){
            const float dA = __expf(dv*Av[n]);
            P[n] *= dA;
            h[n] = dA*h[n] + du*Bv[n];
          }
        }
        float* Pp = Pend + ((size_t)(b*CH+c)*D_INNER + d)*16;
        float* Hp = Hend + ((size_t)(b*CH+c)*D_INNER + d)*16;
        *(float4*)(Pp+ 0) = make_float4(P[0],P[1],P[2],P[3]);
        *(float4*)(Pp+ 4) = make_float4(P[4],P[5],P[6],P[7]);
        *(float4*)(Pp+ 8) = make_float4(P[8],P[9],P[10],P[11]);
        *(float4*)(Pp+12) = make_float4(P[12],P[13],P[14],P[15]);
        *(float4*)(Hp+ 0) = make_float4(h[0],h[1],h[2],h[3]);
        *(float4*)(Hp+ 4) = make_float4(h[4],h[5],h[6],h[7]);
        *(float4*)(Hp+ 8) = make_float4(h[8],h[9],h[10],h[11]);
        *(float4*)(Hp+12) = make_float4(h[12],h[13],h[14],h[15]);
      }
      gsync(bar, bi++);
    }
    // ---- S8: scan pass3 w/ inline prefix combine -> ybf (384 vblocks) ----
    {
      const float* alog = A_log + (size_t)l*1536*16;
      const float* Dpar = D_param + (size_t)l*1536;
      for (int vb = blk; vb < 6*B_SZ*CH; vb += NBLK){
        const int x = vb % 6, b = (vb/6) % B_SZ, c = vb / (6*B_SZ);
        const int d = x*256 + tid;
        float4 t0 = *(const float4*)(alog + d*16 + 0);
        float4 t1 = *(const float4*)(alog + d*16 + 4);
        float4 t2 = *(const float4*)(alog + d*16 + 8);
        float4 t3 = *(const float4*)(alog + d*16 + 12);
        float Av[16] = {t0.x,t0.y,t0.z,t0.w,t1.x,t1.y,t1.z,t1.w,
                        t2.x,t2.y,t2.z,t2.w,t3.x,t3.y,t3.z,t3.w};
        float h[16];
        #pragma unroll
        for (int n=0;n<16;n++){ Av[n] = -__expf(Av[n]); h[n] = 0.f; }
        for (int cc=0; cc<c; cc++){
          const float* Pp = Pend + ((size_t)(b*CH+cc)*D_INNER + d)*16;
          const float* Hp = Hend + ((size_t)(b*CH+cc)*D_INNER + d)*16;
          float4 p0 = *(const float4*)(Pp+0),  p1 = *(const float4*)(Pp+4);
          float4 p2 = *(const float4*)(Pp+8),  p3 = *(const float4*)(Pp+12);
          float4 q0 = *(const float4*)(Hp+0),  q1 = *(const float4*)(Hp+4);
          float4 q2 = *(const float4*)(Hp+8),  q3 = *(const float4*)(Hp+12);
          const float Pv[16] = {p0.x,p0.y,p0.z,p0.w,p1.x,p1.y,p1.z,p1.w,
                                p2.x,p2.y,p2.z,p2.w,p3.x,p3.y,p3.z,p3.w};
          const float Hv[16] = {q0.x,q0.y,q0.z,q0.w,q1.x,q1.y,q1.z,q1.w,
                                q2.x,q2.y,q2.z,q2.w,q3.x,q3.y,q3.z,q3.w};
          #pragma unroll
          for (int n=0;n<16;n++) h[n] = Pv[n]*h[n] + Hv[n];
        }
        const float Dv = Dpar[d];
        const size_t r0 = (size_t)b*T_SZ + (size_t)c*CT;
        const float* dp = delta + r0*D_INNER + d;
        const float* up = ucv  + r0*D_INNER + d;
        const float* bp = xp   + r0*XP_N + 48;
        const float* cp = xp   + r0*XP_N + 64;
        const float* zp = xz   + r0*3072 + 1536 + d;
        unsigned short* yp = ybf + r0*D_INNER + d;
        for (int t=0;t<CT;t++){
          const float dv = dp[(size_t)t*D_INNER];
          const float uv = up[(size_t)t*D_INNER];
          const float zv = zp[(size_t)t*3072];
          const float4 B0 = *(const float4*)(bp + (size_t)t*XP_N);
          const float4 B1 = *(const float4*)(bp + (size_t)t*XP_N + 4);
          const float4 B2 = *(const float4*)(bp + (size_t)t*XP_N + 8);
          const float4 B3 = *(const float4*)(bp + (size_t)t*XP_N + 12);
          const float4 C0 = *(const float4*)(cp + (size_t)t*XP_N);
          const float4 C1 = *(const float4*)(cp + (size_t)t*XP_N + 4);
          const float4 C2 = *(const float4*)(cp + (size_t)t*XP_N + 8);
          const float4 C3 = *(const float4*)(cp + (size_t)t*XP_N + 12);
          const float Bv[16] = {B0.x,B0.y,B0.z,B0.w,B1.x,B1.y,B1.z,B1.w,
                                B2.x,B2.y,B2.z,B2.w,B3.x,B3.y,B3.z,B3.w};
          const float Cv[16] = {C0.x,C0.y,C0.z,C0.w,C1.x,C1.y,C1.z,C1.w,
                                C2.x,C2.y,C2.z,C2.w,C3.x,C3.y,C3.z,C3.w};
          const float du = dv*uv;
          float p = 0.f;
          #pragma unroll
          for (int n=0;n<16;n++){
            const float dA = __expf(dv*Av[n]);
            h[n] = dA*h[n] + du*Bv[n];
            p += h[n]*Cv[n];
          }
          yp[(size_t)t*D_INNER] = f2bf((p + uv*Dv)*siluf_(zv));
        }
      }
      gsync(bar, bi++);
    }
    // ---- S9: out_proj split-K: ybf @ wbo_l^T -> partials delta/ucv (384 tiles) ----
    {
      const unsigned short* Wl = wbo + (size_t)l*768*1536;
      for (int vb = blk; vb < 6*16*OS; vb += NBLK){
        const int bn = (vb % 6)*128, bm = ((vb/6) % 16)*128, s = vb / 96;
        const int koff = s*OKC;
        f32x4 acc[4][4] = {};
        const unsigned short* Ag = ybf + (size_t)(bm + row0g)*1536 + koff + khl*8;
        const unsigned short* Wg = Wl  + (size_t)(bn + row0g)*1536 + koff + khl*8;
        kloop(Ag, Wg, (size_t)64*1536, (size_t)64*1536, OKC, As, Ws, woff, wm, wn, fr, quad, acc);
        float* Cbuf = (s < 2 ? delta : ucv) + (size_t)(s & 1)*MN_OUT;
        #pragma unroll
        for (int i=0;i<4;i++)
          #pragma unroll
          for (int r=0;r<4;r++){
            const int row = bm + wm + i*16 + quad*4 + r;
            float* Cp = Cbuf + (size_t)row*768 + bn + wn + fr;
            #pragma unroll
            for (int j=0;j<4;j++) Cp[j*16] = acc[i][j][r];
          }
      }
      gsync(bar, bi++);
    }
  }

  // ---- final: resid += partials, fp32 rmsnorm(norm_f_w) -> normed ----
  for (int row = blk; row < 2048; row += NBLK){
    float v[3]; float ss = 0.f;
    #pragma unroll
    for (int i=0;i<3;i++){
      const int c = tid + i*256;
      const size_t idx = (size_t)row*768 + c;
      float r = resid[idx] + (delta[idx] + delta[MN_OUT + idx]) + (ucv[idx] + ucv[MN_OUT + idx]);
      v[i] = r; ss += r*r;
    }
    #pragma unroll
    for (int off=32; off>=1; off>>=1) ss += __shfl_xor(ss, off);
    if (lane64 == 0) sred[wv] = ss;
    __syncthreads();
    const float tot = sred[0]+sred[1]+sred[2]+sred[3];
    const float scale = rsqrtf(tot*(1.0f/768.0f) + 1e-5f);
    #pragma unroll
    for (int i=0;i<3;i++){
      const int c = tid + i*256;
      normed[(size_t)row*768 + c] = v[i]*scale*norm_f_w[c];
    }
    __syncthreads();
  }
  gsync(bar, bi++);

  // ---- pool partial (192 vblocks) ----
  for (int vb = blk; vb < 192; vb += NBLK){
    const int bx = vb % 12, s = vb / 12;
    const int i = bx*256 + tid;
    const int b = i / 768, m = i % 768;
    float sum = 0.f;
    const float* p = normed + ((size_t)b*T_SZ + s*32)*768 + m;
    #pragma unroll
    for (int t=0; t<32; t++) sum += p[(size_t)t*768];
    ppool[s*3072 + i] = sum;
  }
  gsync(bar, bi++);

  // ---- pool final + classifier (blocks 0..3) ----
  for (int vb = blk; vb < 4; vb += NBLK){
    const int b = vb;
    #pragma unroll
    for (int i=0;i<3;i++){
      const int m = tid + i*256;
      float s = 0.f;
      #pragma unroll
      for (int c=0;c<16;c++) s += ppool[c*3072 + b*768 + m];
      lspool[m] = s * (1.0f/T_SZ);
    }
    __syncthreads();
    for (int o = wv; o < 10; o += 4){
      float s = 0.f;
      for (int k = lane64; k < 768; k += 64) s += lspool[k]*cls_w[o*768 + k];
      #pragma unroll
      for (int off=32; off>=1; off>>=1) s += __shfl_xor(s, off);
      if (lane64 == 0) out[b*10 + o] = s + cls_b[o];
    }
  }
}

extern "C" void kernel_launch(void* const* d_in, const int* in_sizes, int n_in,
                              void* d_out, int out_size, void* d_ws, size_t ws_size,
                              hipStream_t stream) {
  const float* x         = (const float*)d_in[0];
  const float* in_proj_w = (const float*)d_in[1];
  const float* conv_w    = (const float*)d_in[2];
  const float* conv_b    = (const float*)d_in[3];
  const float* x_proj_w  = (const float*)d_in[4];
  const float* dt_proj_w = (const float*)d_in[5];
  const float* dt_proj_b = (const float*)d_in[6];
  const float* A_log     = (const float*)d_in[7];
  const float* D_param   = (const float*)d_in[8];
  const float* out_proj_w= (const float*)d_in[9];
  const float* norm_w    = (const float*)d_in[10];
  const float* norm_f_w  = (const float*)d_in[11];
  const float* inp_w     = (const float*)d_in[12];
  const float* inp_b     = (const float*)d_in[13];
  const float* cls_w     = (const float*)d_in[14];
  const float* cls_b     = (const float*)d_in[15];
  float* out = (float*)d_out;

  char* ws = (char*)d_ws;
  auto carve = [&](size_t nelem)->float* {
    float* p = (float*)ws;
    ws += ((nelem*sizeof(float) + 255)/256)*256;
    return p;
  };
  float* xtb_f  = carve((size_t)ROWS*256/2);
  float* resid  = carve((size_t)ROWS*768);
  float* normed = carve((size_t)ROWS*768);   // bf16 normed / Pend during scan / fp32 final
  float* hidden = carve((size_t)ROWS*768);   // Hend during scan
  float* xz     = carve((size_t)ROWS*3072);
  float* ucv    = carve((size_t)ROWS*1536);  // out_proj partials s=2,3 after scan
  float* xp     = carve((size_t)ROWS*XP_N);
  float* delta  = carve((size_t)ROWS*1536);  // out_proj partials s=0,1 after scan
  float* ybf_f  = carve((size_t)ROWS*1536/2);
  float* ubf_f  = carve((size_t)ROWS*1536/2);
  float* xpb_f  = carve((size_t)ROWS*64/2);
  float* wbi_f  = carve((size_t)CA_N0/2);
  float* wbo_f  = carve((size_t)CA_N1/2);
  float* wip_f  = carve((size_t)CA_N2/2);
  float* wxp_f  = carve((size_t)CA_N3/2);
  float* wdt_f  = carve((size_t)CA_N4/2);
  float* xpart  = carve((size_t)XS*ROWS*XP_N);
  float* ppool  = carve((size_t)16*3072);
  unsigned* bar = (unsigned*)carve(64);

  unsigned short* xtb = (unsigned short*)xtb_f;
  unsigned short* ybf = (unsigned short*)ybf_f;
  unsigned short* ubf = (unsigned short*)ubf_f;
  unsigned short* xpb = (unsigned short*)xpb_f;
  unsigned short* wbi = (unsigned short*)wbi_f;
  unsigned short* wbo = (unsigned short*)wbo_f;
  unsigned short* wip = (unsigned short*)wip_f;
  unsigned short* wxp = (unsigned short*)wxp_f;
  unsigned short* wdt = (unsigned short*)wdt_f;

  hipMemsetAsync(bar, 0, 64*sizeof(unsigned), stream);
  cast_all<<<15168, 256, 0, stream>>>(in_proj_w, wbi, out_proj_w, wbo,
                                      inp_w, wip, x_proj_w, wxp, dt_proj_w, wdt);
  transpose_x<<<dim3(16,8,4), dim3(32,32), 0, stream>>>(x, xtb);
  gemm_input<<<dim3(6,16), 256, 0, stream>>>(xtb, wip, inp_b, resid);
  mamba_mega<<<NBLK, 256, 0, stream>>>(conv_w, conv_b, dt_proj_b, A_log, D_param,
                                       norm_w, norm_f_w, cls_w, cls_b,
                                       wbi, wbo, wxp, wdt,
                                       resid, normed, hidden, xz, ucv, xp, delta,
                                       ybf, ubf, xpb, xpart, ppool, out, bar);
}

// Round 10
// 876.168 us; speedup vs baseline: 5.9253x; 5.9253x over previous
//
#include <hip/hip_runtime.h>
#include <math.h>

#define D_MODEL 768
#define D_INNER 1536
#define B_SZ 4
#define T_SZ 512
#define ROWS (B_SZ*T_SZ)   // 2048
#define XP_N 80
#define CH 16              // scan chunks
#define CT 32              // T per chunk
#define XS 8               // x_proj split-K factor
#define XKC (D_INNER/XS)   // 192
#define OS 4               // out_proj split-K factor
#define OKC (D_INNER/OS)   // 384
#define MN_OUT (ROWS*768)  // 1572864

typedef __attribute__((ext_vector_type(8))) short bf16x8;
typedef __attribute__((ext_vector_type(4))) float f32x4;

#define GLL(g, l) __builtin_amdgcn_global_load_lds( \
    (const __attribute__((address_space(1))) void*)(g), \
    (__attribute__((address_space(3))) void*)(l), 16, 0, 0)

__device__ __forceinline__ float sigmoidf_(float x){ return 1.0f/(1.0f+__expf(-x)); }
__device__ __forceinline__ float siluf_(float x){ return x*sigmoidf_(x); }
__device__ __forceinline__ unsigned short f2bf(float f){
  unsigned u = __builtin_bit_cast(unsigned, f);
  u = (u + 0x7FFFu + ((u >> 16) & 1u)) >> 16;   // RNE
  return (unsigned short)u;
}
__device__ __forceinline__ float bf2f(unsigned short v){
  return __builtin_bit_cast(float, (unsigned)v << 16);
}
__device__ __forceinline__ ushort4 cvt4(float4 v){
  ushort4 r; r.x=f2bf(v.x); r.y=f2bf(v.y); r.z=f2bf(v.z); r.w=f2bf(v.w); return r;
}

// ---------------- one-time cast of ALL layer weights to bf16 (w/ padding) ----------------
#define CA_N0 9437184LL
#define CA_N1 4718592LL
#define CA_N2 196608LL
#define CA_N3 786432LL
#define CA_N4 393216LL
__global__ __launch_bounds__(256) void cast_all(
    const float* __restrict__ ipw, unsigned short* __restrict__ wbi,
    const float* __restrict__ opw, unsigned short* __restrict__ wbo,
    const float* __restrict__ inpw, unsigned short* __restrict__ inpwb,
    const float* __restrict__ xpw, unsigned short* __restrict__ xpwb,
    const float* __restrict__ dtw, unsigned short* __restrict__ dtwb)
{
  long long i4 = ((long long)blockIdx.x*256 + threadIdx.x)*4;
  if (i4 < CA_N0){ *(ushort4*)(wbi + i4) = cvt4(*(const float4*)(ipw + i4)); return; }
  i4 -= CA_N0;
  if (i4 < CA_N1){ *(ushort4*)(wbo + i4) = cvt4(*(const float4*)(opw + i4)); return; }
  i4 -= CA_N1;
  if (i4 < CA_N2){ *(ushort4*)(inpwb + i4) = cvt4(*(const float4*)(inpw + i4)); return; }
  i4 -= CA_N2;
  if (i4 < CA_N3){
    const long long l = i4 / (128*1536), rem = i4 % (128*1536);
    const long long r = rem / 1536, k = rem % 1536;
    ushort4 o;
    if (r < 80) o = cvt4(*(const float4*)(xpw + (l*80 + r)*1536 + k));
    else { o.x=0;o.y=0;o.z=0;o.w=0; }
    *(ushort4*)(xpwb + i4) = o; return;
  }
  i4 -= CA_N3;
  if (i4 < CA_N4){
    const long long l = i4 / (1536*64), rem = i4 % (1536*64);
    const long long r = rem / 64, c = rem % 64;
    ushort4 o;
    if (c < 48) o = cvt4(*(const float4*)(dtw + (l*1536 + r)*48 + c));
    else { o.x=0;o.y=0;o.z=0;o.w=0; }
    *(ushort4*)(dtwb + i4) = o;
  }
}

// ---------------- transpose: x (B,256,512) -> xtb (B,512,256) bf16 ----------------
__global__ void transpose_x(const float* __restrict__ x, unsigned short* __restrict__ xtb){
  __shared__ float s[32][33];
  int b = blockIdx.z;
  int t0 = blockIdx.x*32, c0 = blockIdx.y*32;
  int tx = threadIdx.x, ty = threadIdx.y;
  s[ty][tx] = x[((size_t)b*256 + (c0+ty))*512 + (t0+tx)];
  __syncthreads();
  xtb[((size_t)b*512 + (t0+ty))*256 + (c0+tx)] = f2bf(s[tx][ty]);
}

// ---------------- input GEMM: xtb @ wip^T + bias -> resid fp32 (K=256) ----------------
__global__ __launch_bounds__(256) void gemm_input(
    const unsigned short* __restrict__ A, const unsigned short* __restrict__ Wb,
    const float* __restrict__ bias, float* __restrict__ C)
{
  __shared__ unsigned short As[128*32];
  __shared__ unsigned short Ws[128*32];
  const int tid = threadIdx.x;
  const int bm = blockIdx.y*128, bn = blockIdx.x*128;
  const int wave = tid >> 6, lane = tid & 63;
  const int wm = (wave >> 1)*64, wn = (wave & 1)*64;
  const int fr = lane & 15, quad = lane >> 4;
  f32x4 acc[4][4] = {};
  const int row0 = (wave*64 + lane) >> 2;
  const int khl  = ((lane & 3) + 4 - ((row0 >> 1) & 3)) & 3;
  const unsigned short* Ag = A  + (size_t)(bm + row0)*256 + khl*8;
  const unsigned short* Wg = Wb + (size_t)(bn + row0)*256 + khl*8;
  const size_t rstep = (size_t)64*256;
  unsigned short* ldsA = As + wave*512;
  unsigned short* ldsW = Ws + wave*512;
  for (int k0 = 0; k0 < 256; k0 += 32){
    GLL(Ag + k0,          ldsA);
    GLL(Ag + rstep + k0,  ldsA + 2048);
    GLL(Wg + k0,          ldsW);
    GLL(Wg + rstep + k0,  ldsW + 2048);
    __syncthreads();
    bf16x8 a[4], b[4];
    #pragma unroll
    for (int i=0;i<4;i++){
      const int row = wm + i*16 + fr;
      a[i] = *(const bf16x8*)(As + row*32 + (((quad + (row>>1)) & 3)*8));
    }
    #pragma unroll
    for (int j=0;j<4;j++){
      const int row = wn + j*16 + fr;
      b[j] = *(const bf16x8*)(Ws + row*32 + (((quad + (row>>1)) & 3)*8));
    }
    #pragma unroll
    for (int i=0;i<4;i++)
      #pragma unroll
      for (int j=0;j<4;j++)
        acc[i][j] = __builtin_amdgcn_mfma_f32_16x16x32_bf16(a[i], b[j], acc[i][j], 0, 0, 0);
    __syncthreads();
  }
  #pragma unroll
  for (int i=0;i<4;i++)
    #pragma unroll
    for (int r=0;r<4;r++){
      const int row = bm + wm + i*16 + quad*4 + r;
      #pragma unroll
      for (int j=0;j<4;j++){
        const int col = bn + wn + j*16 + fr;
        C[(size_t)row*768 + col] = acc[i][j][r] + bias[col];
      }
    }
}

// ---------------- in_proj GEMM: normedb @ wbi^T -> xzb bf16 (K=768) ----------------
__global__ __launch_bounds__(256) void gemm_inproj(
    const unsigned short* __restrict__ A, const unsigned short* __restrict__ Wb,
    unsigned short* __restrict__ Cb)
{
  __shared__ unsigned short As[128*32];
  __shared__ unsigned short Ws[128*32];
  const int tid = threadIdx.x;
  const int bm = blockIdx.y*128, bn = blockIdx.x*128;
  const int wave = tid >> 6, lane = tid & 63;
  const int wm = (wave >> 1)*64, wn = (wave & 1)*64;
  const int fr = lane & 15, quad = lane >> 4;
  f32x4 acc[4][4] = {};
  const int row0 = (wave*64 + lane) >> 2;
  const int khl  = ((lane & 3) + 4 - ((row0 >> 1) & 3)) & 3;
  const unsigned short* Ag = A  + (size_t)(bm + row0)*768 + khl*8;
  const unsigned short* Wg = Wb + (size_t)(bn + row0)*768 + khl*8;
  const size_t rstep = (size_t)64*768;
  unsigned short* ldsA = As + wave*512;
  unsigned short* ldsW = Ws + wave*512;
  for (int k0 = 0; k0 < 768; k0 += 32){
    GLL(Ag + k0,          ldsA);
    GLL(Ag + rstep + k0,  ldsA + 2048);
    GLL(Wg + k0,          ldsW);
    GLL(Wg + rstep + k0,  ldsW + 2048);
    __syncthreads();
    bf16x8 a[4], b[4];
    #pragma unroll
    for (int i=0;i<4;i++){
      const int row = wm + i*16 + fr;
      a[i] = *(const bf16x8*)(As + row*32 + (((quad + (row>>1)) & 3)*8));
    }
    #pragma unroll
    for (int j=0;j<4;j++){
      const int row = wn + j*16 + fr;
      b[j] = *(const bf16x8*)(Ws + row*32 + (((quad + (row>>1)) & 3)*8));
    }
    #pragma unroll
    for (int i=0;i<4;i++)
      #pragma unroll
      for (int j=0;j<4;j++)
        acc[i][j] = __builtin_amdgcn_mfma_f32_16x16x32_bf16(a[i], b[j], acc[i][j], 0, 0, 0);
    __syncthreads();
  }
  #pragma unroll
  for (int i=0;i<4;i++)
    #pragma unroll
    for (int r=0;r<4;r++){
      const int row = bm + wm + i*16 + quad*4 + r;
      #pragma unroll
      for (int j=0;j<4;j++){
        const int col = bn + wn + j*16 + fr;
        Cb[(size_t)row*3072 + col] = f2bf(acc[i][j][r]);
      }
    }
}

// ---------------- x_proj GEMM with inline conv+silu (A computed on the fly) ----------------
// grid (16 bm-tiles, XS). A = u[128][192] built in LDS from xzb; W via GLL; partials out.
__global__ __launch_bounds__(256) void gemm_xp_fused(
    const unsigned short* __restrict__ xzb, const float* __restrict__ cw,
    const float* __restrict__ cb, const unsigned short* __restrict__ Wl,
    float* __restrict__ part)
{
  __shared__ unsigned short AsAll[6*128*32];   // 48 KB: whole 128x192 A tile, swizzled per 32-chunk
  __shared__ unsigned short Ws[128*32];
  const int tid = threadIdx.x;
  const int bm = blockIdx.x*128;
  const int s  = blockIdx.y;
  const int koff = s*XKC;
  // phase A: u = silu(conv(xz_u)) -> LDS bf16
  for (int task = tid; task < 128*24; task += 256){
    const int rl = task / 24, c8 = task % 24;
    const int r = bm + rl;
    const int t = r & (T_SZ-1);
    const int d0 = koff + c8*8;
    float acc[8];
    float4 cb0 = *(const float4*)(cb + d0);
    float4 cb1 = *(const float4*)(cb + d0 + 4);
    acc[0]=cb0.x; acc[1]=cb0.y; acc[2]=cb0.z; acc[3]=cb0.w;
    acc[4]=cb1.x; acc[5]=cb1.y; acc[6]=cb1.z; acc[7]=cb1.w;
    float4 cwv[8];
    #pragma unroll
    for (int j=0;j<8;j++) cwv[j] = *(const float4*)(cw + (size_t)(d0+j)*4);
    #pragma unroll
    for (int k=0;k<4;k++){
      const int tt = t - 3 + k;
      if (tt >= 0){
        bf16x8 xv = *(const bf16x8*)(xzb + (size_t)(r-3+k)*3072 + d0);
        #pragma unroll
        for (int j=0;j<8;j++)
          acc[j] += bf2f((unsigned short)xv[j]) * ((const float*)&cwv[j])[k];
      }
    }
    bf16x8 ov;
    #pragma unroll
    for (int j=0;j<8;j++) ov[j] = (short)f2bf(siluf_(acc[j]));
    const int kk = c8 >> 2, khl = c8 & 3;
    const int khp = (khl + (rl >> 1)) & 3;
    *(bf16x8*)(AsAll + kk*4096 + rl*32 + khp*8) = ov;
  }
  // phase B: K-loop (A persistent in LDS; W via GLL)
  const int wave = tid >> 6, lane = tid & 63;
  const int wm = (wave >> 1)*64, wn = (wave & 1)*64;
  const int fr = lane & 15, quad = lane >> 4;
  const int row0 = (wave*64 + lane) >> 2;
  const int khl2 = ((lane & 3) + 4 - ((row0 >> 1) & 3)) & 3;
  const unsigned short* Wg = Wl + (size_t)row0*D_INNER + koff + khl2*8;
  const size_t rstepW = (size_t)64*D_INNER;
  unsigned short* ldsW = Ws + wave*512;
  f32x4 accm[4][4] = {};
  for (int k0 = 0; k0 < XKC; k0 += 32){
    GLL(Wg + k0,           ldsW);
    GLL(Wg + rstepW + k0,  ldsW + 2048);
    __syncthreads();                    // covers phase-A writes on first iter
    const unsigned short* Ak = AsAll + (k0 >> 5)*4096;
    bf16x8 a[4], b[4];
    #pragma unroll
    for (int i=0;i<4;i++){
      const int row = wm + i*16 + fr;
      a[i] = *(const bf16x8*)(Ak + row*32 + (((quad + (row>>1)) & 3)*8));
    }
    #pragma unroll
    for (int j=0;j<4;j++){
      const int row = wn + j*16 + fr;
      b[j] = *(const bf16x8*)(Ws + row*32 + (((quad + (row>>1)) & 3)*8));
    }
    #pragma unroll
    for (int i=0;i<4;i++)
      #pragma unroll
      for (int j=0;j<4;j++)
        accm[i][j] = __builtin_amdgcn_mfma_f32_16x16x32_bf16(a[i], b[j], accm[i][j], 0, 0, 0);
    __syncthreads();
  }
  #pragma unroll
  for (int i=0;i<4;i++)
    #pragma unroll
    for (int r=0;r<4;r++){
      const int row = bm + wm + i*16 + quad*4 + r;
      #pragma unroll
      for (int j=0;j<4;j++){
        const int col = wn + j*16 + fr;
        if (col < XP_N)
          part[((size_t)s*ROWS + row)*XP_N + col] = accm[i][j][r];
      }
    }
}

// ---------------- dt_proj GEMM with inline partial-reduce (+ xp emit) ----------------
// grid (12 bn, 16 bm). Reduces xpart into LDS A (bf16, padded K=64); bn==0 writes xp fp32.
__global__ __launch_bounds__(256) void gemm_dt_fused(
    const float* __restrict__ xpart, const unsigned short* __restrict__ Wl,
    const float* __restrict__ bias, float* __restrict__ xp, float* __restrict__ delta)
{
  __shared__ unsigned short AsAll[2*128*32];   // 16 KB
  __shared__ unsigned short Ws[128*32];
  const int tid = threadIdx.x;
  const int bn = blockIdx.x*128, bm = blockIdx.y*128;
  // zero A (pad cols 48..63)
  {
    bf16x8 zv = {0,0,0,0,0,0,0,0};
    for (int i = tid; i < 1024; i += 256) *(bf16x8*)(AsAll + i*8) = zv;
  }
  __syncthreads();
  // phase A: reduce 8 partials; cols<48 -> LDS bf16; bn==0 also writes xp fp32 (80 cols)
  for (int task = tid; task < 128*10; task += 256){
    const int rl = task / 10, c8 = task % 10;
    const int row = bm + rl;
    const int col0 = c8*8;
    float4 sa = make_float4(0.f,0.f,0.f,0.f), sb = make_float4(0.f,0.f,0.f,0.f);
    #pragma unroll
    for (int k=0;k<XS;k++){
      const float* pp = xpart + ((size_t)k*ROWS + row)*XP_N + col0;
      float4 a = *(const float4*)pp;
      float4 b = *(const float4*)(pp + 4);
      sa.x+=a.x; sa.y+=a.y; sa.z+=a.z; sa.w+=a.w;
      sb.x+=b.x; sb.y+=b.y; sb.z+=b.z; sb.w+=b.w;
    }
    if (c8 < 6){
      bf16x8 ov;
      ov[0]=(short)f2bf(sa.x); ov[1]=(short)f2bf(sa.y); ov[2]=(short)f2bf(sa.z); ov[3]=(short)f2bf(sa.w);
      ov[4]=(short)f2bf(sb.x); ov[5]=(short)f2bf(sb.y); ov[6]=(short)f2bf(sb.z); ov[7]=(short)f2bf(sb.w);
      const int kk = c8 >> 2, khl = c8 & 3;
      const int khp = (khl + (rl >> 1)) & 3;
      *(bf16x8*)(AsAll + kk*4096 + rl*32 + khp*8) = ov;
    }
    if (bn == 0){
      *(float4*)(xp + (size_t)row*XP_N + col0)     = sa;
      *(float4*)(xp + (size_t)row*XP_N + col0 + 4) = sb;
    }
  }
  // phase B: K=64 (2 iters)
  const int wave = tid >> 6, lane = tid & 63;
  const int wm = (wave >> 1)*64, wn = (wave & 1)*64;
  const int fr = lane & 15, quad = lane >> 4;
  const int row0 = (wave*64 + lane) >> 2;
  const int khl2 = ((lane & 3) + 4 - ((row0 >> 1) & 3)) & 3;
  const unsigned short* Wg = Wl + (size_t)(bn + row0)*64 + khl2*8;
  const size_t rstepW = (size_t)64*64;
  unsigned short* ldsW = Ws + wave*512;
  f32x4 accm[4][4] = {};
  for (int k0 = 0; k0 < 64; k0 += 32){
    GLL(Wg + k0,           ldsW);
    GLL(Wg + rstepW + k0,  ldsW + 2048);
    __syncthreads();
    const unsigned short* Ak = AsAll + (k0 >> 5)*4096;
    bf16x8 a[4], b[4];
    #pragma unroll
    for (int i=0;i<4;i++){
      const int row = wm + i*16 + fr;
      a[i] = *(const bf16x8*)(Ak + row*32 + (((quad + (row>>1)) & 3)*8));
    }
    #pragma unroll
    for (int j=0;j<4;j++){
      const int row = wn + j*16 + fr;
      b[j] = *(const bf16x8*)(Ws + row*32 + (((quad + (row>>1)) & 3)*8));
    }
    #pragma unroll
    for (int i=0;i<4;i++)
      #pragma unroll
      for (int j=0;j<4;j++)
        accm[i][j] = __builtin_amdgcn_mfma_f32_16x16x32_bf16(a[i], b[j], accm[i][j], 0, 0, 0);
    __syncthreads();
  }
  #pragma unroll
  for (int i=0;i<4;i++)
    #pragma unroll
    for (int r=0;r<4;r++){
      const int row = bm + wm + i*16 + quad*4 + r;
      float* Cp = delta + (size_t)row*D_INNER + bn + wn + fr;
      #pragma unroll
      for (int j=0;j<4;j++){
        const int col = bn + wn + j*16 + fr;
        float v = accm[i][j][r] + bias[col];
        v = (v > 20.f) ? v : log1pf(__expf(v));
        Cp[j*16] = v;
      }
    }
}

// ---------------- out_proj split-K GEMM (ybf @ wbo^T -> partials) ----------------
__global__ __launch_bounds__(256) void gemm_bf16_sk(
    const unsigned short* __restrict__ A, const unsigned short* __restrict__ Wb,
    float* __restrict__ P0, float* __restrict__ P1)
{
  __shared__ unsigned short As[128*32];
  __shared__ unsigned short Ws[128*32];
  const int tid = threadIdx.x;
  const int bm = blockIdx.y*128, bn = blockIdx.x*128;
  const int s = blockIdx.z;
  const int koff = s*OKC;
  const int wave = tid >> 6, lane = tid & 63;
  const int wm = (wave >> 1)*64, wn = (wave & 1)*64;
  const int fr = lane & 15, quad = lane >> 4;
  f32x4 acc[4][4] = {};
  const int row0 = (wave*64 + lane) >> 2;
  const int khl  = ((lane & 3) + 4 - ((row0 >> 1) & 3)) & 3;
  const unsigned short* Ag = A  + (size_t)(bm + row0)*1536 + koff + khl*8;
  const unsigned short* Wg = Wb + (size_t)(bn + row0)*1536 + koff + khl*8;
  const size_t rstep = (size_t)64*1536;
  unsigned short* ldsA = As + wave*512;
  unsigned short* ldsW = Ws + wave*512;
  for (int k0 = 0; k0 < OKC; k0 += 32){
    GLL(Ag + k0,          ldsA);
    GLL(Ag + rstep + k0,  ldsA + 2048);
    GLL(Wg + k0,          ldsW);
    GLL(Wg + rstep + k0,  ldsW + 2048);
    __syncthreads();
    bf16x8 a[4], b[4];
    #pragma unroll
    for (int i=0;i<4;i++){
      const int row = wm + i*16 + fr;
      a[i] = *(const bf16x8*)(As + row*32 + (((quad + (row>>1)) & 3)*8));
    }
    #pragma unroll
    for (int j=0;j<4;j++){
      const int row = wn + j*16 + fr;
      b[j] = *(const bf16x8*)(Ws + row*32 + (((quad + (row>>1)) & 3)*8));
    }
    #pragma unroll
    for (int i=0;i<4;i++)
      #pragma unroll
      for (int j=0;j<4;j++)
        acc[i][j] = __builtin_amdgcn_mfma_f32_16x16x32_bf16(a[i], b[j], acc[i][j], 0, 0, 0);
    __syncthreads();
  }
  float* Cbuf = (s < 2 ? P0 : P1) + (size_t)(s & 1)*MN_OUT;
  #pragma unroll
  for (int i=0;i<4;i++)
    #pragma unroll
    for (int r=0;r<4;r++){
      const int row = bm + wm + i*16 + quad*4 + r;
      float* Cp = Cbuf + (size_t)row*768 + bn + wn + fr;
      #pragma unroll
      for (int j=0;j<4;j++)
        Cp[j*16] = acc[i][j][r];
    }
}

// ---------------- fused: [out_proj partial-reduce +] residual add + RMSNorm ----------------
__global__ __launch_bounds__(256) void fused_norm(
    float* __restrict__ resid, const float* __restrict__ P0, const float* __restrict__ P1,
    const float* __restrict__ w, unsigned short* __restrict__ obf, float* __restrict__ ofp)
{
  const int row = blockIdx.x;
  const int tid = threadIdx.x;
  float v[3];
  float ss = 0.f;
  #pragma unroll
  for (int i=0;i<3;i++){
    const int c = tid + i*256;
    const size_t idx = (size_t)row*768 + c;
    float r = resid[idx];
    if (P0) r += (P0[idx] + P0[MN_OUT + idx]) + (P1[idx] + P1[MN_OUT + idx]);
    v[i] = r;
    ss += r*r;
  }
  #pragma unroll
  for (int off=32; off>=1; off>>=1) ss += __shfl_xor(ss, off);
  __shared__ float sred[4];
  const int lane = tid & 63, wv = tid >> 6;
  if (lane == 0) sred[wv] = ss;
  __syncthreads();
  const float tot = sred[0]+sred[1]+sred[2]+sred[3];
  const float scale = rsqrtf(tot*(1.0f/768.0f) + 1e-5f);
  #pragma unroll
  for (int i=0;i<3;i++){
    const int c = tid + i*256;
    const size_t idx = (size_t)row*768 + c;
    if (P0) resid[idx] = v[i];
    const float o = v[i]*scale*w[c];
    if (obf) obf[idx] = f2bf(o);
    else     ofp[idx] = o;
  }
}

// ---------------- scan pass1 with inline rolling conv ----------------
__global__ __launch_bounds__(256) void scan_pass1(
    const float* __restrict__ delta, const unsigned short* __restrict__ xzb,
    const float* __restrict__ cw, const float* __restrict__ cb,
    const float* __restrict__ xp, const float* __restrict__ alog,
    float* __restrict__ Pend, float* __restrict__ Hend)
{
  const int d = blockIdx.x*256 + threadIdx.x;
  const int b = blockIdx.y, c = blockIdx.z;
  float4 t0v = *(const float4*)(alog + d*16 + 0);
  float4 t1v = *(const float4*)(alog + d*16 + 4);
  float4 t2v = *(const float4*)(alog + d*16 + 8);
  float4 t3v = *(const float4*)(alog + d*16 + 12);
  float Av[16] = {t0v.x,t0v.y,t0v.z,t0v.w,t1v.x,t1v.y,t1v.z,t1v.w,
                  t2v.x,t2v.y,t2v.z,t2v.w,t3v.x,t3v.y,t3v.z,t3v.w};
  float h[16], P[16];
  #pragma unroll
  for (int n=0;n<16;n++){ Av[n] = -__expf(Av[n]); h[n]=0.f; P[n]=1.f; }
  const float4 cwv = *(const float4*)(cw + (size_t)d*4);
  const float cbd = cb[d];
  const size_t row0 = (size_t)b*T_SZ + (size_t)c*CT;
  const float* dp = delta + row0*D_INNER + d;
  const float* bp = xp    + row0*XP_N + 48;
  const unsigned short* xzp = xzb + row0*3072 + d;
  float xm3 = (c > 0) ? bf2f(xzp[-3*3072]) : 0.f;
  float xm2 = (c > 0) ? bf2f(xzp[-2*3072]) : 0.f;
  float xm1 = (c > 0) ? bf2f(xzp[-1*3072]) : 0.f;
  for (int t=0;t<CT;t++){
    const float dv = dp[(size_t)t*D_INNER];
    const float xc = bf2f(xzp[(size_t)t*3072]);
    float ac = cbd;
    ac += xm3*cwv.x; ac += xm2*cwv.y; ac += xm1*cwv.z; ac += xc*cwv.w;
    const float uv = siluf_(ac);
    xm3 = xm2; xm2 = xm1; xm1 = xc;
    const float4 B0 = *(const float4*)(bp + (size_t)t*XP_N);
    const float4 B1 = *(const float4*)(bp + (size_t)t*XP_N + 4);
    const float4 B2 = *(const float4*)(bp + (size_t)t*XP_N + 8);
    const float4 B3 = *(const float4*)(bp + (size_t)t*XP_N + 12);
    const float Bv[16] = {B0.x,B0.y,B0.z,B0.w,B1.x,B1.y,B1.z,B1.w,
                          B2.x,B2.y,B2.z,B2.w,B3.x,B3.y,B3.z,B3.w};
    const float du = dv*uv;
    #pragma unroll
    for (int n=0;n<16;n++){
      const float dA = __expf(dv*Av[n]);
      P[n] *= dA;
      h[n] = dA*h[n] + du*Bv[n];
    }
  }
  float* Pp = Pend + ((size_t)(b*CH+c)*D_INNER + d)*16;
  float* Hp = Hend + ((size_t)(b*CH+c)*D_INNER + d)*16;
  *(float4*)(Pp+ 0) = make_float4(P[0],P[1],P[2],P[3]);
  *(float4*)(Pp+ 4) = make_float4(P[4],P[5],P[6],P[7]);
  *(float4*)(Pp+ 8) = make_float4(P[8],P[9],P[10],P[11]);
  *(float4*)(Pp+12) = make_float4(P[12],P[13],P[14],P[15]);
  *(float4*)(Hp+ 0) = make_float4(h[0],h[1],h[2],h[3]);
  *(float4*)(Hp+ 4) = make_float4(h[4],h[5],h[6],h[7]);
  *(float4*)(Hp+ 8) = make_float4(h[8],h[9],h[10],h[11]);
  *(float4*)(Hp+12) = make_float4(h[12],h[13],h[14],h[15]);
}

// ---------------- scan pass3: prefix combine + rolling conv + y emit (bf16) ----------------
__global__ __launch_bounds__(256) void scan_pass3(
    const float* __restrict__ delta, const unsigned short* __restrict__ xzb,
    const float* __restrict__ cw, const float* __restrict__ cb,
    const float* __restrict__ xp, const float* __restrict__ alog,
    const float* __restrict__ Dp, const float* __restrict__ Pend,
    const float* __restrict__ Hend, unsigned short* __restrict__ yb)
{
  const int d = blockIdx.x*256 + threadIdx.x;
  const int b = blockIdx.y, c = blockIdx.z;
  float4 t0v = *(const float4*)(alog + d*16 + 0);
  float4 t1v = *(const float4*)(alog + d*16 + 4);
  float4 t2v = *(const float4*)(alog + d*16 + 8);
  float4 t3v = *(const float4*)(alog + d*16 + 12);
  float Av[16] = {t0v.x,t0v.y,t0v.z,t0v.w,t1v.x,t1v.y,t1v.z,t1v.w,
                  t2v.x,t2v.y,t2v.z,t2v.w,t3v.x,t3v.y,t3v.z,t3v.w};
  float h[16];
  #pragma unroll
  for (int n=0;n<16;n++){ Av[n] = -__expf(Av[n]); h[n] = 0.f; }
  for (int cc=0; cc<c; cc++){
    const float* Pp = Pend + ((size_t)(b*CH+cc)*D_INNER + d)*16;
    const float* Hp = Hend + ((size_t)(b*CH+cc)*D_INNER + d)*16;
    float4 p0 = *(const float4*)(Pp+0),  p1 = *(const float4*)(Pp+4);
    float4 p2 = *(const float4*)(Pp+8),  p3 = *(const float4*)(Pp+12);
    float4 q0 = *(const float4*)(Hp+0),  q1 = *(const float4*)(Hp+4);
    float4 q2 = *(const float4*)(Hp+8),  q3 = *(const float4*)(Hp+12);
    const float Pv[16] = {p0.x,p0.y,p0.z,p0.w,p1.x,p1.y,p1.z,p1.w,
                          p2.x,p2.y,p2.z,p2.w,p3.x,p3.y,p3.z,p3.w};
    const float Hv[16] = {q0.x,q0.y,q0.z,q0.w,q1.x,q1.y,q1.z,q1.w,
                          q2.x,q2.y,q2.z,q2.w,q3.x,q3.y,q3.z,q3.w};
    #pragma unroll
    for (int n=0;n<16;n++) h[n] = Pv[n]*h[n] + Hv[n];
  }
  const float Dv = Dp[d];
  const float4 cwv = *(const float4*)(cw + (size_t)d*4);
  const float cbd = cb[d];
  const size_t row0 = (size_t)b*T_SZ + (size_t)c*CT;
  const float* dp = delta + row0*D_INNER + d;
  const float* bp = xp    + row0*XP_N + 48;
  const float* cp = xp    + row0*XP_N + 64;
  const unsigned short* xzp = xzb + row0*3072 + d;
  const unsigned short* zp  = xzb + row0*3072 + 1536 + d;
  unsigned short* yp = yb + row0*D_INNER + d;
  float xm3 = (c > 0) ? bf2f(xzp[-3*3072]) : 0.f;
  float xm2 = (c > 0) ? bf2f(xzp[-2*3072]) : 0.f;
  float xm1 = (c > 0) ? bf2f(xzp[-1*3072]) : 0.f;
  for (int t=0;t<CT;t++){
    const float dv = dp[(size_t)t*D_INNER];
    const float xc = bf2f(xzp[(size_t)t*3072]);
    float ac = cbd;
    ac += xm3*cwv.x; ac += xm2*cwv.y; ac += xm1*cwv.z; ac += xc*cwv.w;
    const float uv = siluf_(ac);
    xm3 = xm2; xm2 = xm1; xm1 = xc;
    const float zv = bf2f(zp[(size_t)t*3072]);
    const float4 B0 = *(const float4*)(bp + (size_t)t*XP_N);
    const float4 B1 = *(const float4*)(bp + (size_t)t*XP_N + 4);
    const float4 B2 = *(const float4*)(bp + (size_t)t*XP_N + 8);
    const float4 B3 = *(const float4*)(bp + (size_t)t*XP_N + 12);
    const float4 C0 = *(const float4*)(cp + (size_t)t*XP_N);
    const float4 C1 = *(const float4*)(cp + (size_t)t*XP_N + 4);
    const float4 C2 = *(const float4*)(cp + (size_t)t*XP_N + 8);
    const float4 C3 = *(const float4*)(cp + (size_t)t*XP_N + 12);
    const float Bv[16] = {B0.x,B0.y,B0.z,B0.w,B1.x,B1.y,B1.z,B1.w,
                          B2.x,B2.y,B2.z,B2.w,B3.x,B3.y,B3.z,B3.w};
    const float Cv[16] = {C0.x,C0.y,C0.z,C0.w,C1.x,C1.y,C1.z,C1.w,
                          C2.x,C2.y,C2.z,C2.w,C3.x,C3.y,C3.z,C3.w};
    const float du = dv*uv;
    float p = 0.f;
    #pragma unroll
    for (int n=0;n<16;n++){
      const float dA = __expf(dv*Av[n]);
      h[n] = dA*h[n] + du*Bv[n];
      p += h[n]*Cv[n];
    }
    yp[(size_t)t*D_INNER] = f2bf((p + uv*Dv)*siluf_(zv));
  }
}

// ---------------- mean pool stage 1 ----------------
__global__ __launch_bounds__(256) void pool_partial(const float* __restrict__ normed,
                                                    float* __restrict__ part){
  const int i = blockIdx.x*256 + threadIdx.x;
  const int s = blockIdx.y;
  const int b = i / 768, m = i % 768;
  float sum = 0.f;
  const float* p = normed + ((size_t)b*T_SZ + s*32)*768 + m;
  #pragma unroll
  for (int t=0; t<32; t++) sum += p[(size_t)t*768];
  part[s*3072 + i] = sum;
}

// ---------------- fused pool-final + classifier ----------------
__global__ __launch_bounds__(256) void pool_cls(const float* __restrict__ part,
                                                const float* __restrict__ cw,
                                                const float* __restrict__ cb,
                                                float* __restrict__ out){
  __shared__ float ls[768];
  const int b = blockIdx.x;
  const int tid = threadIdx.x;
  #pragma unroll
  for (int i=0;i<3;i++){
    const int m = tid + i*256;
    float s = 0.f;
    #pragma unroll
    for (int c=0;c<16;c++) s += part[c*3072 + b*768 + m];
    ls[m] = s * (1.0f/T_SZ);
  }
  __syncthreads();
  const int wave = tid >> 6, lane = tid & 63;
  for (int o = wave; o < 10; o += 4){
    float s = 0.f;
    for (int k = lane; k < 768; k += 64) s += ls[k]*cw[o*768 + k];
    #pragma unroll
    for (int off=32; off>=1; off>>=1) s += __shfl_xor(s, off);
    if (lane == 0) out[b*10 + o] = s + cb[o];
  }
}

extern "C" void kernel_launch(void* const* d_in, const int* in_sizes, int n_in,
                              void* d_out, int out_size, void* d_ws, size_t ws_size,
                              hipStream_t stream) {
  const float* x         = (const float*)d_in[0];
  const float* in_proj_w = (const float*)d_in[1];
  const float* conv_w    = (const float*)d_in[2];
  const float* conv_b    = (const float*)d_in[3];
  const float* x_proj_w  = (const float*)d_in[4];
  const float* dt_proj_w = (const float*)d_in[5];
  const float* dt_proj_b = (const float*)d_in[6];
  const float* A_log     = (const float*)d_in[7];
  const float* D_param   = (const float*)d_in[8];
  const float* out_proj_w= (const float*)d_in[9];
  const float* norm_w    = (const float*)d_in[10];
  const float* norm_f_w  = (const float*)d_in[11];
  const float* inp_w     = (const float*)d_in[12];
  const float* inp_b     = (const float*)d_in[13];
  const float* cls_w     = (const float*)d_in[14];
  const float* cls_b     = (const float*)d_in[15];
  float* out = (float*)d_out;

  char* ws = (char*)d_ws;
  auto carve = [&](size_t nelem)->float* {
    float* p = (float*)ws;
    ws += ((nelem*sizeof(float) + 255)/256)*256;
    return p;
  };
  float* xtb_f  = carve((size_t)ROWS*256/2);
  float* resid  = carve((size_t)ROWS*768);
  float* normed = carve((size_t)ROWS*768);   // bf16 normed / Pend during scan / fp32 final
  float* hidden = carve((size_t)ROWS*768);   // Hend during scan
  float* xzb_f  = carve((size_t)ROWS*3072/2);
  float* pbuf2  = carve((size_t)ROWS*1536);  // out_proj partials s=2,3
  float* xp     = carve((size_t)ROWS*XP_N);
  float* delta  = carve((size_t)ROWS*1536);  // dt output; out_proj partials s=0,1 after scan
  float* ybf_f  = carve((size_t)ROWS*1536/2);
  float* wbi_f  = carve((size_t)CA_N0/2);
  float* wbo_f  = carve((size_t)CA_N1/2);
  float* wip_f  = carve((size_t)CA_N2/2);
  float* wxp_f  = carve((size_t)CA_N3/2);
  float* wdt_f  = carve((size_t)CA_N4/2);
  float* xpart  = carve((size_t)XS*ROWS*XP_N);
  float* ppool  = carve((size_t)16*3072);

  unsigned short* xtb = (unsigned short*)xtb_f;
  unsigned short* normedb = (unsigned short*)normed;
  unsigned short* xzb = (unsigned short*)xzb_f;
  unsigned short* ybf = (unsigned short*)ybf_f;
  unsigned short* wbi = (unsigned short*)wbi_f;
  unsigned short* wbo = (unsigned short*)wbo_f;
  unsigned short* wip = (unsigned short*)wip_f;
  unsigned short* wxp = (unsigned short*)wxp_f;
  unsigned short* wdt = (unsigned short*)wdt_f;
  float* Pend = normed;    // dead during scan
  float* Hend = hidden;    // dead during scan

  cast_all<<<15168, 256, 0, stream>>>(in_proj_w, wbi, out_proj_w, wbo,
                                      inp_w, wip, x_proj_w, wxp, dt_proj_w, wdt);
  transpose_x<<<dim3(16,8,4), dim3(32,32), 0, stream>>>(x, xtb);
  gemm_input<<<dim3(6,16), 256, 0, stream>>>(xtb, wip, inp_b, resid);

  for (int l = 0; l < 4; l++){
    fused_norm<<<2048, 256, 0, stream>>>(resid, l ? delta : nullptr, l ? pbuf2 : nullptr,
                                         norm_w + (size_t)l*768, normedb, nullptr);
    gemm_inproj<<<dim3(24,16), 256, 0, stream>>>(normedb, wbi + (size_t)l*3072*768, xzb);
    gemm_xp_fused<<<dim3(16,XS), 256, 0, stream>>>(xzb, conv_w + (size_t)l*1536*4,
                                                   conv_b + (size_t)l*1536,
                                                   wxp + (size_t)l*128*1536, xpart);
    gemm_dt_fused<<<dim3(12,16), 256, 0, stream>>>(xpart, wdt + (size_t)l*1536*64,
                                                   dt_proj_b + (size_t)l*1536, xp, delta);
    scan_pass1<<<dim3(6,B_SZ,CH-1), 256, 0, stream>>>(delta, xzb,
                                                      conv_w + (size_t)l*1536*4,
                                                      conv_b + (size_t)l*1536, xp,
                                                      A_log + (size_t)l*1536*16, Pend, Hend);
    scan_pass3<<<dim3(6,B_SZ,CH), 256, 0, stream>>>(delta, xzb,
                                                    conv_w + (size_t)l*1536*4,
                                                    conv_b + (size_t)l*1536, xp,
                                                    A_log + (size_t)l*1536*16,
                                                    D_param + (size_t)l*1536, Pend, Hend, ybf);
    gemm_bf16_sk<<<dim3(6,16,OS), 256, 0, stream>>>(ybf, wbo + (size_t)l*768*1536,
                                                    delta, pbuf2);
  }

  fused_norm<<<2048, 256, 0, stream>>>(resid, delta, pbuf2, norm_f_w, nullptr, normed);
  pool_partial<<<dim3(12,16), 256, 0, stream>>>(normed, ppool);
  pool_cls<<<4, 256, 0, stream>>>(ppool, cls_w, cls_b, out);
}

// Round 11
// 838.260 us; speedup vs baseline: 6.1933x; 1.0452x over previous
//
#include <hip/hip_runtime.h>
#include <math.h>

#define D_MODEL 768
#define D_INNER 1536
#define B_SZ 4
#define T_SZ 512
#define ROWS (B_SZ*T_SZ)   // 2048
#define XP_N 80
#define CH 16              // scan chunks
#define CT 32              // T per chunk
#define XS 16              // x_proj split-K factor
#define XKC (D_INNER/XS)   // 96
#define OS 4               // out_proj split-K factor
#define OKC (D_INNER/OS)   // 384
#define MN_OUT (ROWS*768)  // 1572864

typedef __attribute__((ext_vector_type(8))) short bf16x8;
typedef __attribute__((ext_vector_type(4))) float f32x4;

#define GLL(g, l) __builtin_amdgcn_global_load_lds( \
    (const __attribute__((address_space(1))) void*)(g), \
    (__attribute__((address_space(3))) void*)(l), 16, 0, 0)

__device__ __forceinline__ float sigmoidf_(float x){ return 1.0f/(1.0f+__expf(-x)); }
__device__ __forceinline__ float siluf_(float x){ return x*sigmoidf_(x); }
__device__ __forceinline__ unsigned short f2bf(float f){
  unsigned u = __builtin_bit_cast(unsigned, f);
  u = (u + 0x7FFFu + ((u >> 16) & 1u)) >> 16;   // RNE
  return (unsigned short)u;
}
__device__ __forceinline__ float bf2f(unsigned short v){
  return __builtin_bit_cast(float, (unsigned)v << 16);
}
__device__ __forceinline__ ushort4 cvt4(float4 v){
  ushort4 r; r.x=f2bf(v.x); r.y=f2bf(v.y); r.z=f2bf(v.z); r.w=f2bf(v.w); return r;
}

// ---------------- one-time cast of ALL layer weights to bf16 (w/ padding) ----------------
#define CA_N0 9437184LL
#define CA_N1 4718592LL
#define CA_N2 196608LL
#define CA_N3 786432LL
#define CA_N4 393216LL
__global__ __launch_bounds__(256) void cast_all(
    const float* __restrict__ ipw, unsigned short* __restrict__ wbi,
    const float* __restrict__ opw, unsigned short* __restrict__ wbo,
    const float* __restrict__ inpw, unsigned short* __restrict__ inpwb,
    const float* __restrict__ xpw, unsigned short* __restrict__ xpwb,
    const float* __restrict__ dtw, unsigned short* __restrict__ dtwb)
{
  long long i4 = ((long long)blockIdx.x*256 + threadIdx.x)*4;
  if (i4 < CA_N0){ *(ushort4*)(wbi + i4) = cvt4(*(const float4*)(ipw + i4)); return; }
  i4 -= CA_N0;
  if (i4 < CA_N1){ *(ushort4*)(wbo + i4) = cvt4(*(const float4*)(opw + i4)); return; }
  i4 -= CA_N1;
  if (i4 < CA_N2){ *(ushort4*)(inpwb + i4) = cvt4(*(const float4*)(inpw + i4)); return; }
  i4 -= CA_N2;
  if (i4 < CA_N3){
    const long long l = i4 / (128*1536), rem = i4 % (128*1536);
    const long long r = rem / 1536, k = rem % 1536;
    ushort4 o;
    if (r < 80) o = cvt4(*(const float4*)(xpw + (l*80 + r)*1536 + k));
    else { o.x=0;o.y=0;o.z=0;o.w=0; }
    *(ushort4*)(xpwb + i4) = o; return;
  }
  i4 -= CA_N3;
  if (i4 < CA_N4){
    const long long l = i4 / (1536*64), rem = i4 % (1536*64);
    const long long r = rem / 64, c = rem % 64;
    ushort4 o;
    if (c < 48) o = cvt4(*(const float4*)(dtw + (l*1536 + r)*48 + c));
    else { o.x=0;o.y=0;o.z=0;o.w=0; }
    *(ushort4*)(dtwb + i4) = o;
  }
}

// ---------------- transpose: x (B,256,512) -> xtb (B,512,256) bf16 ----------------
__global__ void transpose_x(const float* __restrict__ x, unsigned short* __restrict__ xtb){
  __shared__ float s[32][33];
  int b = blockIdx.z;
  int t0 = blockIdx.x*32, c0 = blockIdx.y*32;
  int tx = threadIdx.x, ty = threadIdx.y;
  s[ty][tx] = x[((size_t)b*256 + (c0+ty))*512 + (t0+tx)];
  __syncthreads();
  xtb[((size_t)b*512 + (t0+ty))*256 + (c0+tx)] = f2bf(s[tx][ty]);
}

// ---------------- input GEMM: xtb @ wip^T + bias -> resid fp32 (K=256) ----------------
__global__ __launch_bounds__(256) void gemm_input(
    const unsigned short* __restrict__ A, const unsigned short* __restrict__ Wb,
    const float* __restrict__ bias, float* __restrict__ C)
{
  __shared__ unsigned short As[128*32];
  __shared__ unsigned short Ws[128*32];
  const int tid = threadIdx.x;
  const int bm = blockIdx.y*128, bn = blockIdx.x*128;
  const int wave = tid >> 6, lane = tid & 63;
  const int wm = (wave >> 1)*64, wn = (wave & 1)*64;
  const int fr = lane & 15, quad = lane >> 4;
  f32x4 acc[4][4] = {};
  const int row0 = (wave*64 + lane) >> 2;
  const int khl  = ((lane & 3) + 4 - ((row0 >> 1) & 3)) & 3;
  const unsigned short* Ag = A  + (size_t)(bm + row0)*256 + khl*8;
  const unsigned short* Wg = Wb + (size_t)(bn + row0)*256 + khl*8;
  const size_t rstep = (size_t)64*256;
  unsigned short* ldsA = As + wave*512;
  unsigned short* ldsW = Ws + wave*512;
  for (int k0 = 0; k0 < 256; k0 += 32){
    GLL(Ag + k0,          ldsA);
    GLL(Ag + rstep + k0,  ldsA + 2048);
    GLL(Wg + k0,          ldsW);
    GLL(Wg + rstep + k0,  ldsW + 2048);
    __syncthreads();
    bf16x8 a[4], b[4];
    #pragma unroll
    for (int i=0;i<4;i++){
      const int row = wm + i*16 + fr;
      a[i] = *(const bf16x8*)(As + row*32 + (((quad + (row>>1)) & 3)*8));
    }
    #pragma unroll
    for (int j=0;j<4;j++){
      const int row = wn + j*16 + fr;
      b[j] = *(const bf16x8*)(Ws + row*32 + (((quad + (row>>1)) & 3)*8));
    }
    #pragma unroll
    for (int i=0;i<4;i++)
      #pragma unroll
      for (int j=0;j<4;j++)
        acc[i][j] = __builtin_amdgcn_mfma_f32_16x16x32_bf16(a[i], b[j], acc[i][j], 0, 0, 0);
    __syncthreads();
  }
  #pragma unroll
  for (int i=0;i<4;i++)
    #pragma unroll
    for (int r=0;r<4;r++){
      const int row = bm + wm + i*16 + quad*4 + r;
      #pragma unroll
      for (int j=0;j<4;j++){
        const int col = bn + wn + j*16 + fr;
        C[(size_t)row*768 + col] = acc[i][j][r] + bias[col];
      }
    }
}

// ---------------- in_proj GEMM: normedb @ wbi^T -> xzb bf16 (K=768) ----------------
__global__ __launch_bounds__(256) void gemm_inproj(
    const unsigned short* __restrict__ A, const unsigned short* __restrict__ Wb,
    unsigned short* __restrict__ Cb)
{
  __shared__ unsigned short As[128*32];
  __shared__ unsigned short Ws[128*32];
  const int tid = threadIdx.x;
  const int bm = blockIdx.y*128, bn = blockIdx.x*128;
  const int wave = tid >> 6, lane = tid & 63;
  const int wm = (wave >> 1)*64, wn = (wave & 1)*64;
  const int fr = lane & 15, quad = lane >> 4;
  f32x4 acc[4][4] = {};
  const int row0 = (wave*64 + lane) >> 2;
  const int khl  = ((lane & 3) + 4 - ((row0 >> 1) & 3)) & 3;
  const unsigned short* Ag = A  + (size_t)(bm + row0)*768 + khl*8;
  const unsigned short* Wg = Wb + (size_t)(bn + row0)*768 + khl*8;
  const size_t rstep = (size_t)64*768;
  unsigned short* ldsA = As + wave*512;
  unsigned short* ldsW = Ws + wave*512;
  for (int k0 = 0; k0 < 768; k0 += 32){
    GLL(Ag + k0,          ldsA);
    GLL(Ag + rstep + k0,  ldsA + 2048);
    GLL(Wg + k0,          ldsW);
    GLL(Wg + rstep + k0,  ldsW + 2048);
    __syncthreads();
    bf16x8 a[4], b[4];
    #pragma unroll
    for (int i=0;i<4;i++){
      const int row = wm + i*16 + fr;
      a[i] = *(const bf16x8*)(As + row*32 + (((quad + (row>>1)) & 3)*8));
    }
    #pragma unroll
    for (int j=0;j<4;j++){
      const int row = wn + j*16 + fr;
      b[j] = *(const bf16x8*)(Ws + row*32 + (((quad + (row>>1)) & 3)*8));
    }
    #pragma unroll
    for (int i=0;i<4;i++)
      #pragma unroll
      for (int j=0;j<4;j++)
        acc[i][j] = __builtin_amdgcn_mfma_f32_16x16x32_bf16(a[i], b[j], acc[i][j], 0, 0, 0);
    __syncthreads();
  }
  #pragma unroll
  for (int i=0;i<4;i++)
    #pragma unroll
    for (int r=0;r<4;r++){
      const int row = bm + wm + i*16 + quad*4 + r;
      #pragma unroll
      for (int j=0;j<4;j++){
        const int col = bn + wn + j*16 + fr;
        Cb[(size_t)row*3072 + col] = f2bf(acc[i][j][r]);
      }
    }
}

// ---------------- causal conv (K=4) + silu: xzb -> ubf bf16 only ----------------
__global__ __launch_bounds__(256) void conv_silu(
    const unsigned short* __restrict__ xzb, const float* __restrict__ cw,
    const float* __restrict__ cb, unsigned short* __restrict__ ub)
{
  const int idx = blockIdx.x*256 + threadIdx.x;
  if (idx >= ROWS*D_INNER) return;
  const int d = idx % D_INNER;
  const int row = idx / D_INNER;
  const int t = row & (T_SZ-1);
  float acc = cb[d];
  #pragma unroll
  for (int k=0;k<4;k++){
    const int tt = t - 3 + k;
    if (tt >= 0)
      acc += bf2f(xzb[(size_t)(row - 3 + k)*3072 + d]) * cw[d*4 + k];
  }
  ub[idx] = f2bf(siluf_(acc));
}

// ---------------- x_proj bf16 split-K (GLL-staged): partials (s,row,80) ----------------
// grid (16 bm, XS=16). A = ubf (2048x1536), W = wxp (128x1536 zero-padded rows).
__global__ __launch_bounds__(256) void gemm_bf16_xp(
    const unsigned short* __restrict__ A, const unsigned short* __restrict__ Wb,
    float* __restrict__ part)
{
  __shared__ unsigned short As[128*32];
  __shared__ unsigned short Ws[128*32];
  const int tid = threadIdx.x;
  const int bm = blockIdx.x*128;
  const int s = blockIdx.y;
  const int koff = s*XKC;
  const int wave = tid >> 6, lane = tid & 63;
  const int wm = (wave >> 1)*64, wn = (wave & 1)*64;
  const int fr = lane & 15, quad = lane >> 4;
  f32x4 acc[4][4] = {};
  const int row0 = (wave*64 + lane) >> 2;
  const int khl  = ((lane & 3) + 4 - ((row0 >> 1) & 3)) & 3;
  const unsigned short* Ag = A  + (size_t)(bm + row0)*D_INNER + koff + khl*8;
  const unsigned short* Wg = Wb + (size_t)row0*D_INNER + koff + khl*8;
  const size_t rstep = (size_t)64*D_INNER;
  unsigned short* ldsA = As + wave*512;
  unsigned short* ldsW = Ws + wave*512;
  for (int k0 = 0; k0 < XKC; k0 += 32){
    GLL(Ag + k0,          ldsA);
    GLL(Ag + rstep + k0,  ldsA + 2048);
    GLL(Wg + k0,          ldsW);
    GLL(Wg + rstep + k0,  ldsW + 2048);
    __syncthreads();
    bf16x8 a[4], b[4];
    #pragma unroll
    for (int i=0;i<4;i++){
      const int row = wm + i*16 + fr;
      a[i] = *(const bf16x8*)(As + row*32 + (((quad + (row>>1)) & 3)*8));
    }
    #pragma unroll
    for (int j=0;j<4;j++){
      const int row = wn + j*16 + fr;
      b[j] = *(const bf16x8*)(Ws + row*32 + (((quad + (row>>1)) & 3)*8));
    }
    #pragma unroll
    for (int i=0;i<4;i++)
      #pragma unroll
      for (int j=0;j<4;j++)
        acc[i][j] = __builtin_amdgcn_mfma_f32_16x16x32_bf16(a[i], b[j], acc[i][j], 0, 0, 0);
    __syncthreads();
  }
  #pragma unroll
  for (int i=0;i<4;i++)
    #pragma unroll
    for (int r=0;r<4;r++){
      const int row = bm + wm + i*16 + quad*4 + r;
      #pragma unroll
      for (int j=0;j<4;j++){
        const int col = wn + j*16 + fr;
        if (col < XP_N)
          part[((size_t)s*ROWS + row)*XP_N + col] = acc[i][j][r];
      }
    }
}

// ---------------- dt_proj GEMM with inline partial-reduce (+ xp emit) ----------------
// grid (12 bn, 16 bm). Reduces XS xpart slices into LDS A (bf16, K=64 padded);
// bn==0 blocks also write xp fp32 (80 cols).
__global__ __launch_bounds__(256) void gemm_dt_fused(
    const float* __restrict__ xpart, const unsigned short* __restrict__ Wl,
    const float* __restrict__ bias, float* __restrict__ xp, float* __restrict__ delta)
{
  __shared__ unsigned short AsAll[2*128*32];   // 16 KB
  __shared__ unsigned short Ws[128*32];
  const int tid = threadIdx.x;
  const int bn = blockIdx.x*128, bm = blockIdx.y*128;
  {
    bf16x8 zv = {0,0,0,0,0,0,0,0};
    for (int i = tid; i < 1024; i += 256) *(bf16x8*)(AsAll + i*8) = zv;
  }
  __syncthreads();
  for (int task = tid; task < 128*10; task += 256){
    const int rl = task / 10, c8 = task % 10;
    const int row = bm + rl;
    const int col0 = c8*8;
    float4 sa = make_float4(0.f,0.f,0.f,0.f), sb = make_float4(0.f,0.f,0.f,0.f);
    #pragma unroll
    for (int k=0;k<XS;k++){
      const float* pp = xpart + ((size_t)k*ROWS + row)*XP_N + col0;
      float4 a = *(const float4*)pp;
      float4 b = *(const float4*)(pp + 4);
      sa.x+=a.x; sa.y+=a.y; sa.z+=a.z; sa.w+=a.w;
      sb.x+=b.x; sb.y+=b.y; sb.z+=b.z; sb.w+=b.w;
    }
    if (c8 < 6){
      bf16x8 ov;
      ov[0]=(short)f2bf(sa.x); ov[1]=(short)f2bf(sa.y); ov[2]=(short)f2bf(sa.z); ov[3]=(short)f2bf(sa.w);
      ov[4]=(short)f2bf(sb.x); ov[5]=(short)f2bf(sb.y); ov[6]=(short)f2bf(sb.z); ov[7]=(short)f2bf(sb.w);
      const int kk = c8 >> 2, khl = c8 & 3;
      const int khp = (khl + (rl >> 1)) & 3;
      *(bf16x8*)(AsAll + kk*4096 + rl*32 + khp*8) = ov;
    }
    if (bn == 0){
      *(float4*)(xp + (size_t)row*XP_N + col0)     = sa;
      *(float4*)(xp + (size_t)row*XP_N + col0 + 4) = sb;
    }
  }
  const int wave = tid >> 6, lane = tid & 63;
  const int wm = (wave >> 1)*64, wn = (wave & 1)*64;
  const int fr = lane & 15, quad = lane >> 4;
  const int row0 = (wave*64 + lane) >> 2;
  const int khl2 = ((lane & 3) + 4 - ((row0 >> 1) & 3)) & 3;
  const unsigned short* Wg = Wl + (size_t)(bn + row0)*64 + khl2*8;
  const size_t rstepW = (size_t)64*64;
  unsigned short* ldsW = Ws + wave*512;
  f32x4 accm[4][4] = {};
  for (int k0 = 0; k0 < 64; k0 += 32){
    GLL(Wg + k0,           ldsW);
    GLL(Wg + rstepW + k0,  ldsW + 2048);
    __syncthreads();
    const unsigned short* Ak = AsAll + (k0 >> 5)*4096;
    bf16x8 a[4], b[4];
    #pragma unroll
    for (int i=0;i<4;i++){
      const int row = wm + i*16 + fr;
      a[i] = *(const bf16x8*)(Ak + row*32 + (((quad + (row>>1)) & 3)*8));
    }
    #pragma unroll
    for (int j=0;j<4;j++){
      const int row = wn + j*16 + fr;
      b[j] = *(const bf16x8*)(Ws + row*32 + (((quad + (row>>1)) & 3)*8));
    }
    #pragma unroll
    for (int i=0;i<4;i++)
      #pragma unroll
      for (int j=0;j<4;j++)
        accm[i][j] = __builtin_amdgcn_mfma_f32_16x16x32_bf16(a[i], b[j], accm[i][j], 0, 0, 0);
    __syncthreads();
  }
  #pragma unroll
  for (int i=0;i<4;i++)
    #pragma unroll
    for (int r=0;r<4;r++){
      const int row = bm + wm + i*16 + quad*4 + r;
      float* Cp = delta + (size_t)row*D_INNER + bn + wn + fr;
      #pragma unroll
      for (int j=0;j<4;j++){
        const int col = bn + wn + j*16 + fr;
        float v = accm[i][j][r] + bias[col];
        v = (v > 20.f) ? v : log1pf(__expf(v));
        Cp[j*16] = v;
      }
    }
}

// ---------------- out_proj split-K GEMM (ybf @ wbo^T -> partials) ----------------
__global__ __launch_bounds__(256) void gemm_bf16_sk(
    const unsigned short* __restrict__ A, const unsigned short* __restrict__ Wb,
    float* __restrict__ P0, float* __restrict__ P1)
{
  __shared__ unsigned short As[128*32];
  __shared__ unsigned short Ws[128*32];
  const int tid = threadIdx.x;
  const int bm = blockIdx.y*128, bn = blockIdx.x*128;
  const int s = blockIdx.z;
  const int koff = s*OKC;
  const int wave = tid >> 6, lane = tid & 63;
  const int wm = (wave >> 1)*64, wn = (wave & 1)*64;
  const int fr = lane & 15, quad = lane >> 4;
  f32x4 acc[4][4] = {};
  const int row0 = (wave*64 + lane) >> 2;
  const int khl  = ((lane & 3) + 4 - ((row0 >> 1) & 3)) & 3;
  const unsigned short* Ag = A  + (size_t)(bm + row0)*1536 + koff + khl*8;
  const unsigned short* Wg = Wb + (size_t)(bn + row0)*1536 + koff + khl*8;
  const size_t rstep = (size_t)64*1536;
  unsigned short* ldsA = As + wave*512;
  unsigned short* ldsW = Ws + wave*512;
  for (int k0 = 0; k0 < OKC; k0 += 32){
    GLL(Ag + k0,          ldsA);
    GLL(Ag + rstep + k0,  ldsA + 2048);
    GLL(Wg + k0,          ldsW);
    GLL(Wg + rstep + k0,  ldsW + 2048);
    __syncthreads();
    bf16x8 a[4], b[4];
    #pragma unroll
    for (int i=0;i<4;i++){
      const int row = wm + i*16 + fr;
      a[i] = *(const bf16x8*)(As + row*32 + (((quad + (row>>1)) & 3)*8));
    }
    #pragma unroll
    for (int j=0;j<4;j++){
      const int row = wn + j*16 + fr;
      b[j] = *(const bf16x8*)(Ws + row*32 + (((quad + (row>>1)) & 3)*8));
    }
    #pragma unroll
    for (int i=0;i<4;i++)
      #pragma unroll
      for (int j=0;j<4;j++)
        acc[i][j] = __builtin_amdgcn_mfma_f32_16x16x32_bf16(a[i], b[j], acc[i][j], 0, 0, 0);
    __syncthreads();
  }
  float* Cbuf = (s < 2 ? P0 : P1) + (size_t)(s & 1)*MN_OUT;
  #pragma unroll
  for (int i=0;i<4;i++)
    #pragma unroll
    for (int r=0;r<4;r++){
      const int row = bm + wm + i*16 + quad*4 + r;
      float* Cp = Cbuf + (size_t)row*768 + bn + wn + fr;
      #pragma unroll
      for (int j=0;j<4;j++)
        Cp[j*16] = acc[i][j][r];
    }
}

// ---------------- fused: [out_proj partial-reduce +] residual add + RMSNorm ----------------
__global__ __launch_bounds__(256) void fused_norm(
    float* __restrict__ resid, const float* __restrict__ P0, const float* __restrict__ P1,
    const float* __restrict__ w, unsigned short* __restrict__ obf, float* __restrict__ ofp)
{
  const int row = blockIdx.x;
  const int tid = threadIdx.x;
  float v[3];
  float ss = 0.f;
  #pragma unroll
  for (int i=0;i<3;i++){
    const int c = tid + i*256;
    const size_t idx = (size_t)row*768 + c;
    float r = resid[idx];
    if (P0) r += (P0[idx] + P0[MN_OUT + idx]) + (P1[idx] + P1[MN_OUT + idx]);
    v[i] = r;
    ss += r*r;
  }
  #pragma unroll
  for (int off=32; off>=1; off>>=1) ss += __shfl_xor(ss, off);
  __shared__ float sred[4];
  const int lane = tid & 63, wv = tid >> 6;
  if (lane == 0) sred[wv] = ss;
  __syncthreads();
  const float tot = sred[0]+sred[1]+sred[2]+sred[3];
  const float scale = rsqrtf(tot*(1.0f/768.0f) + 1e-5f);
  #pragma unroll
  for (int i=0;i<3;i++){
    const int c = tid + i*256;
    const size_t idx = (size_t)row*768 + c;
    if (P0) resid[idx] = v[i];
    const float o = v[i]*scale*w[c];
    if (obf) obf[idx] = f2bf(o);
    else     ofp[idx] = o;
  }
}

// ---------------- scan pass1 with inline rolling conv ----------------
__global__ __launch_bounds__(256) void scan_pass1(
    const float* __restrict__ delta, const unsigned short* __restrict__ xzb,
    const float* __restrict__ cw, const float* __restrict__ cb,
    const float* __restrict__ xp, const float* __restrict__ alog,
    float* __restrict__ Pend, float* __restrict__ Hend)
{
  const int d = blockIdx.x*256 + threadIdx.x;
  const int b = blockIdx.y, c = blockIdx.z;
  float4 t0v = *(const float4*)(alog + d*16 + 0);
  float4 t1v = *(const float4*)(alog + d*16 + 4);
  float4 t2v = *(const float4*)(alog + d*16 + 8);
  float4 t3v = *(const float4*)(alog + d*16 + 12);
  float Av[16] = {t0v.x,t0v.y,t0v.z,t0v.w,t1v.x,t1v.y,t1v.z,t1v.w,
                  t2v.x,t2v.y,t2v.z,t2v.w,t3v.x,t3v.y,t3v.z,t3v.w};
  float h[16], P[16];
  #pragma unroll
  for (int n=0;n<16;n++){ Av[n] = -__expf(Av[n]); h[n]=0.f; P[n]=1.f; }
  const float4 cwv = *(const float4*)(cw + (size_t)d*4);
  const float cbd = cb[d];
  const size_t row0 = (size_t)b*T_SZ + (size_t)c*CT;
  const float* dp = delta + row0*D_INNER + d;
  const float* bp = xp    + row0*XP_N + 48;
  const unsigned short* xzp = xzb + row0*3072 + d;
  float xm3 = (c > 0) ? bf2f(xzp[-3*3072]) : 0.f;
  float xm2 = (c > 0) ? bf2f(xzp[-2*3072]) : 0.f;
  float xm1 = (c > 0) ? bf2f(xzp[-1*3072]) : 0.f;
  for (int t=0;t<CT;t++){
    const float dv = dp[(size_t)t*D_INNER];
    const float xc = bf2f(xzp[(size_t)t*3072]);
    float ac = cbd;
    ac += xm3*cwv.x; ac += xm2*cwv.y; ac += xm1*cwv.z; ac += xc*cwv.w;
    const float uv = siluf_(ac);
    xm3 = xm2; xm2 = xm1; xm1 = xc;
    const float4 B0 = *(const float4*)(bp + (size_t)t*XP_N);
    const float4 B1 = *(const float4*)(bp + (size_t)t*XP_N + 4);
    const float4 B2 = *(const float4*)(bp + (size_t)t*XP_N + 8);
    const float4 B3 = *(const float4*)(bp + (size_t)t*XP_N + 12);
    const float Bv[16] = {B0.x,B0.y,B0.z,B0.w,B1.x,B1.y,B1.z,B1.w,
                          B2.x,B2.y,B2.z,B2.w,B3.x,B3.y,B3.z,B3.w};
    const float du = dv*uv;
    #pragma unroll
    for (int n=0;n<16;n++){
      const float dA = __expf(dv*Av[n]);
      P[n] *= dA;
      h[n] = dA*h[n] + du*Bv[n];
    }
  }
  float* Pp = Pend + ((size_t)(b*CH+c)*D_INNER + d)*16;
  float* Hp = Hend + ((size_t)(b*CH+c)*D_INNER + d)*16;
  *(float4*)(Pp+ 0) = make_float4(P[0],P[1],P[2],P[3]);
  *(float4*)(Pp+ 4) = make_float4(P[4],P[5],P[6],P[7]);
  *(float4*)(Pp+ 8) = make_float4(P[8],P[9],P[10],P[11]);
  *(float4*)(Pp+12) = make_float4(P[12],P[13],P[14],P[15]);
  *(float4*)(Hp+ 0) = make_float4(h[0],h[1],h[2],h[3]);
  *(float4*)(Hp+ 4) = make_float4(h[4],h[5],h[6],h[7]);
  *(float4*)(Hp+ 8) = make_float4(h[8],h[9],h[10],h[11]);
  *(float4*)(Hp+12) = make_float4(h[12],h[13],h[14],h[15]);
}

// ---------------- scan pass3: prefix combine + rolling conv + y emit (bf16) ----------------
__global__ __launch_bounds__(256) void scan_pass3(
    const float* __restrict__ delta, const unsigned short* __restrict__ xzb,
    const float* __restrict__ cw, const float* __restrict__ cb,
    const float* __restrict__ xp, const float* __restrict__ alog,
    const float* __restrict__ Dp, const float* __restrict__ Pend,
    const float* __restrict__ Hend, unsigned short* __restrict__ yb)
{
  const int d = blockIdx.x*256 + threadIdx.x;
  const int b = blockIdx.y, c = blockIdx.z;
  float4 t0v = *(const float4*)(alog + d*16 + 0);
  float4 t1v = *(const float4*)(alog + d*16 + 4);
  float4 t2v = *(const float4*)(alog + d*16 + 8);
  float4 t3v = *(const float4*)(alog + d*16 + 12);
  float Av[16] = {t0v.x,t0v.y,t0v.z,t0v.w,t1v.x,t1v.y,t1v.z,t1v.w,
                  t2v.x,t2v.y,t2v.z,t2v.w,t3v.x,t3v.y,t3v.z,t3v.w};
  float h[16];
  #pragma unroll
  for (int n=0;n<16;n++){ Av[n] = -__expf(Av[n]); h[n] = 0.f; }
  for (int cc=0; cc<c; cc++){
    const float* Pp = Pend + ((size_t)(b*CH+cc)*D_INNER + d)*16;
    const float* Hp = Hend + ((size_t)(b*CH+cc)*D_INNER + d)*16;
    float4 p0 = *(const float4*)(Pp+0),  p1 = *(const float4*)(Pp+4);
    float4 p2 = *(const float4*)(Pp+8),  p3 = *(const float4*)(Pp+12);
    float4 q0 = *(const float4*)(Hp+0),  q1 = *(const float4*)(Hp+4);
    float4 q2 = *(const float4*)(Hp+8),  q3 = *(const float4*)(Hp+12);
    const float Pv[16] = {p0.x,p0.y,p0.z,p0.w,p1.x,p1.y,p1.z,p1.w,
                          p2.x,p2.y,p2.z,p2.w,p3.x,p3.y,p3.z,p3.w};
    const float Hv[16] = {q0.x,q0.y,q0.z,q0.w,q1.x,q1.y,q1.z,q1.w,
                          q2.x,q2.y,q2.z,q2.w,q3.x,q3.y,q3.z,q3.w};
    #pragma unroll
    for (int n=0;n<16;n++) h[n] = Pv[n]*h[n] + Hv[n];
  }
  const float Dv = Dp[d];
  const float4 cwv = *(const float4*)(cw + (size_t)d*4);
  const float cbd = cb[d];
  const size_t row0 = (size_t)b*T_SZ + (size_t)c*CT;
  const float* dp = delta + row0*D_INNER + d;
  const float* bp = xp    + row0*XP_N + 48;
  const float* cp = xp    + row0*XP_N + 64;
  const unsigned short* xzp = xzb + row0*3072 + d;
  const unsigned short* zp  = xzb + row0*3072 + 1536 + d;
  unsigned short* yp = yb + row0*D_INNER + d;
  float xm3 = (c > 0) ? bf2f(xzp[-3*3072]) : 0.f;
  float xm2 = (c > 0) ? bf2f(xzp[-2*3072]) : 0.f;
  float xm1 = (c > 0) ? bf2f(xzp[-1*3072]) : 0.f;
  for (int t=0;t<CT;t++){
    const float dv = dp[(size_t)t*D_INNER];
    const float xc = bf2f(xzp[(size_t)t*3072]);
    float ac = cbd;
    ac += xm3*cwv.x; ac += xm2*cwv.y; ac += xm1*cwv.z; ac += xc*cwv.w;
    const float uv = siluf_(ac);
    xm3 = xm2; xm2 = xm1; xm1 = xc;
    const float zv = bf2f(zp[(size_t)t*3072]);
    const float4 B0 = *(const float4*)(bp + (size_t)t*XP_N);
    const float4 B1 = *(const float4*)(bp + (size_t)t*XP_N + 4);
    const float4 B2 = *(const float4*)(bp + (size_t)t*XP_N + 8);
    const float4 B3 = *(const float4*)(bp + (size_t)t*XP_N + 12);
    const float4 C0 = *(const float4*)(cp + (size_t)t*XP_N);
    const float4 C1 = *(const float4*)(cp + (size_t)t*XP_N + 4);
    const float4 C2 = *(const float4*)(cp + (size_t)t*XP_N + 8);
    const float4 C3 = *(const float4*)(cp + (size_t)t*XP_N + 12);
    const float Bv[16] = {B0.x,B0.y,B0.z,B0.w,B1.x,B1.y,B1.z,B1.w,
                          B2.x,B2.y,B2.z,B2.w,B3.x,B3.y,B3.z,B3.w};
    const float Cv[16] = {C0.x,C0.y,C0.z,C0.w,C1.x,C1.y,C1.z,C1.w,
                          C2.x,C2.y,C2.z,C2.w,C3.x,C3.y,C3.z,C3.w};
    const float du = dv*uv;
    float p = 0.f;
    #pragma unroll
    for (int n=0;n<16;n++){
      const float dA = __expf(dv*Av[n]);
      h[n] = dA*h[n] + du*Bv[n];
      p += h[n]*Cv[n];
    }
    yp[(size_t)t*D_INNER] = f2bf((p + uv*Dv)*siluf_(zv));
  }
}

// ---------------- mean pool stage 1 ----------------
__global__ __launch_bounds__(256) void pool_partial(const float* __restrict__ normed,
                                                    float* __restrict__ part){
  const int i = blockIdx.x*256 + threadIdx.x;
  const int s = blockIdx.y;
  const int b = i / 768, m = i % 768;
  float sum = 0.f;
  const float* p = normed + ((size_t)b*T_SZ + s*32)*768 + m;
  #pragma unroll
  for (int t=0; t<32; t++) sum += p[(size_t)t*768];
  part[s*3072 + i] = sum;
}

// ---------------- fused pool-final + classifier ----------------
__global__ __launch_bounds__(256) void pool_cls(const float* __restrict__ part,
                                                const float* __restrict__ cw,
                                                const float* __restrict__ cb,
                                                float* __restrict__ out){
  __shared__ float ls[768];
  const int b = blockIdx.x;
  const int tid = threadIdx.x;
  #pragma unroll
  for (int i=0;i<3;i++){
    const int m = tid + i*256;
    float s = 0.f;
    #pragma unroll
    for (int c=0;c<16;c++) s += part[c*3072 + b*768 + m];
    ls[m] = s * (1.0f/T_SZ);
  }
  __syncthreads();
  const int wave = tid >> 6, lane = tid & 63;
  for (int o = wave; o < 10; o += 4){
    float s = 0.f;
    for (int k = lane; k < 768; k += 64) s += ls[k]*cw[o*768 + k];
    #pragma unroll
    for (int off=32; off>=1; off>>=1) s += __shfl_xor(s, off);
    if (lane == 0) out[b*10 + o] = s + cb[o];
  }
}

extern "C" void kernel_launch(void* const* d_in, const int* in_sizes, int n_in,
                              void* d_out, int out_size, void* d_ws, size_t ws_size,
                              hipStream_t stream) {
  const float* x         = (const float*)d_in[0];
  const float* in_proj_w = (const float*)d_in[1];
  const float* conv_w    = (const float*)d_in[2];
  const float* conv_b    = (const float*)d_in[3];
  const float* x_proj_w  = (const float*)d_in[4];
  const float* dt_proj_w = (const float*)d_in[5];
  const float* dt_proj_b = (const float*)d_in[6];
  const float* A_log     = (const float*)d_in[7];
  const float* D_param   = (const float*)d_in[8];
  const float* out_proj_w= (const float*)d_in[9];
  const float* norm_w    = (const float*)d_in[10];
  const float* norm_f_w  = (const float*)d_in[11];
  const float* inp_w     = (const float*)d_in[12];
  const float* inp_b     = (const float*)d_in[13];
  const float* cls_w     = (const float*)d_in[14];
  const float* cls_b     = (const float*)d_in[15];
  float* out = (float*)d_out;

  char* ws = (char*)d_ws;
  auto carve = [&](size_t nelem)->float* {
    float* p = (float*)ws;
    ws += ((nelem*sizeof(float) + 255)/256)*256;
    return p;
  };
  float* xtb_f  = carve((size_t)ROWS*256/2);
  float* resid  = carve((size_t)ROWS*768);
  float* normed = carve((size_t)ROWS*768);   // bf16 normed / Pend during scan / fp32 final
  float* hidden = carve((size_t)ROWS*768);   // Hend during scan
  float* xzb_f  = carve((size_t)ROWS*3072/2);
  float* pbuf2  = carve((size_t)ROWS*1536);  // out_proj partials s=2,3
  float* xp     = carve((size_t)ROWS*XP_N);
  float* delta  = carve((size_t)ROWS*1536);  // dt out; out_proj partials s=0,1 after scan
  float* ybf_f  = carve((size_t)ROWS*1536/2);
  float* ubf_f  = carve((size_t)ROWS*1536/2);
  float* wbi_f  = carve((size_t)CA_N0/2);
  float* wbo_f  = carve((size_t)CA_N1/2);
  float* wip_f  = carve((size_t)CA_N2/2);
  float* wxp_f  = carve((size_t)CA_N3/2);
  float* wdt_f  = carve((size_t)CA_N4/2);
  float* xpart  = carve((size_t)XS*ROWS*XP_N);
  float* ppool  = carve((size_t)16*3072);

  unsigned short* xtb = (unsigned short*)xtb_f;
  unsigned short* normedb = (unsigned short*)normed;
  unsigned short* xzb = (unsigned short*)xzb_f;
  unsigned short* ybf = (unsigned short*)ybf_f;
  unsigned short* ubf = (unsigned short*)ubf_f;
  unsigned short* wbi = (unsigned short*)wbi_f;
  unsigned short* wbo = (unsigned short*)wbo_f;
  unsigned short* wip = (unsigned short*)wip_f;
  unsigned short* wxp = (unsigned short*)wxp_f;
  unsigned short* wdt = (unsigned short*)wdt_f;
  float* Pend = normed;    // dead during scan
  float* Hend = hidden;    // dead during scan

  cast_all<<<15168, 256, 0, stream>>>(in_proj_w, wbi, out_proj_w, wbo,
                                      inp_w, wip, x_proj_w, wxp, dt_proj_w, wdt);
  transpose_x<<<dim3(16,8,4), dim3(32,32), 0, stream>>>(x, xtb);
  gemm_input<<<dim3(6,16), 256, 0, stream>>>(xtb, wip, inp_b, resid);

  for (int l = 0; l < 4; l++){
    fused_norm<<<2048, 256, 0, stream>>>(resid, l ? delta : nullptr, l ? pbuf2 : nullptr,
                                         norm_w + (size_t)l*768, normedb, nullptr);
    gemm_inproj<<<dim3(24,16), 256, 0, stream>>>(normedb, wbi + (size_t)l*3072*768, xzb);
    conv_silu<<<(ROWS*D_INNER)/256, 256, 0, stream>>>(xzb, conv_w + (size_t)l*1536*4,
                                                      conv_b + (size_t)l*1536, ubf);
    gemm_bf16_xp<<<dim3(16,XS), 256, 0, stream>>>(ubf, wxp + (size_t)l*128*1536, xpart);
    gemm_dt_fused<<<dim3(12,16), 256, 0, stream>>>(xpart, wdt + (size_t)l*1536*64,
                                                   dt_proj_b + (size_t)l*1536, xp, delta);
    scan_pass1<<<dim3(6,B_SZ,CH-1), 256, 0, stream>>>(delta, xzb,
                                                      conv_w + (size_t)l*1536*4,
                                                      conv_b + (size_t)l*1536, xp,
                                                      A_log + (size_t)l*1536*16, Pend, Hend);
    scan_pass3<<<dim3(6,B_SZ,CH), 256, 0, stream>>>(delta, xzb,
                                                    conv_w + (size_t)l*1536*4,
                                                    conv_b + (size_t)l*1536, xp,
                                                    A_log + (size_t)l*1536*16,
                                                    D_param + (size_t)l*1536, Pend, Hend, ybf);
    gemm_bf16_sk<<<dim3(6,16,OS), 256, 0, stream>>>(ybf, wbo + (size_t)l*768*1536,
                                                    delta, pbuf2);
  }

  fused_norm<<<2048, 256, 0, stream>>>(resid, delta, pbuf2, norm_f_w, nullptr, normed);
  pool_partial<<<dim3(12,16), 256, 0, stream>>>(normed, ppool);
  pool_cls<<<4, 256, 0, stream>>>(ppool, cls_w, cls_b, out);
}